// Round 1
// baseline (658.544 us; speedup 1.0000x reference)
//
#include <hip/hip_runtime.h>

#define N_NODES 100000
#define N_EDGES 1600000
#define NFEAT 128
#define NHID 64
#define NCLASS 16

// ---------------------------------------------------------------------------
// Kernel 1: support1 = x @ W1   [N,128] @ [128,64] -> [N,64]
// 256 threads = 4 nodes/block, one thread per (node, hid). x rows staged in
// LDS; W1 read through L1/L2 (32 KB, fully cached after first touch).
// ---------------------------------------------------------------------------
__global__ __launch_bounds__(256) void k_gemm1(const float* __restrict__ x,
                                               const float* __restrict__ W1,
                                               float* __restrict__ support1) {
    __shared__ float xs[4][NFEAT];
    const int tid = threadIdx.x;
    const int node0 = blockIdx.x * 4;

    for (int i = tid; i < 4 * NFEAT; i += 256) {
        int node = node0 + i / NFEAT;
        xs[i / NFEAT][i % NFEAT] = (node < N_NODES) ? x[(size_t)node * NFEAT + (i % NFEAT)] : 0.f;
    }
    __syncthreads();

    const int local = tid / NHID;   // 0..3
    const int j     = tid % NHID;   // 0..63
    const int node  = node0 + local;

    float acc = 0.f;
#pragma unroll 8
    for (int k = 0; k < NFEAT; ++k)
        acc += xs[local][k] * W1[k * NHID + j];

    if (node < N_NODES) support1[(size_t)node * NHID + j] = acc;
}

// ---------------------------------------------------------------------------
// Kernel 2: agg1[dst[e]] += w[e] * support1[src[e]]   (64 feats/edge)
// One 64-lane group per edge; lane j handles feature j. Coalesced gather of
// the source row; fp32 global atomics for the scatter.
// ---------------------------------------------------------------------------
__global__ __launch_bounds__(256) void k_scatter1(const int* __restrict__ src,
                                                  const int* __restrict__ dst,
                                                  const float* __restrict__ ew,
                                                  const float* __restrict__ support1,
                                                  float* __restrict__ agg1) {
    const int e = blockIdx.x * 4 + threadIdx.x / NHID;
    const int j = threadIdx.x % NHID;
    if (e >= N_EDGES) return;
    const int s = src[e];
    const int d = dst[e];
    const float w = ew[e];
    atomicAdd(&agg1[(size_t)d * NHID + j], w * support1[(size_t)s * NHID + j]);
}

// ---------------------------------------------------------------------------
// Kernel 3: support2 = relu(agg1 + b1) @ W2   [N,64] @ [64,16] -> [N,16]
// 256 threads = 16 nodes/block, thread per (node, class). h rows staged in
// LDS (padded +1 to kill the 4-way bank conflict on hs[local][k]).
// ---------------------------------------------------------------------------
__global__ __launch_bounds__(256) void k_gemm2(const float* __restrict__ agg1,
                                               const float* __restrict__ b1,
                                               const float* __restrict__ W2,
                                               float* __restrict__ support2) {
    __shared__ float hs[16][NHID + 1];
    __shared__ float w2s[NHID * NCLASS];
    const int tid = threadIdx.x;
    const int node0 = blockIdx.x * 16;

    for (int i = tid; i < NHID * NCLASS; i += 256) w2s[i] = W2[i];
    for (int i = tid; i < 16 * NHID; i += 256) {
        const int local = i / NHID, k = i % NHID;
        float v = agg1[(size_t)(node0 + local) * NHID + k] + b1[k];
        hs[local][k] = v > 0.f ? v : 0.f;
    }
    __syncthreads();

    const int local = tid / NCLASS;  // 0..15
    const int c     = tid % NCLASS;  // 0..15
    float acc = 0.f;
#pragma unroll
    for (int k = 0; k < NHID; ++k)
        acc += hs[local][k] * w2s[k * NCLASS + c];
    support2[(size_t)(node0 + local) * NCLASS + c] = acc;
}

// ---------------------------------------------------------------------------
// Kernel 4: agg2[dst[e]] += w[e] * support2[src[e]]   (16 feats/edge)
// 16 lanes per edge, 16 edges per block.
// ---------------------------------------------------------------------------
__global__ __launch_bounds__(256) void k_scatter2(const int* __restrict__ src,
                                                  const int* __restrict__ dst,
                                                  const float* __restrict__ ew,
                                                  const float* __restrict__ support2,
                                                  float* __restrict__ agg2) {
    const int e = blockIdx.x * 16 + threadIdx.x / NCLASS;
    const int c = threadIdx.x % NCLASS;
    if (e >= N_EDGES) return;
    atomicAdd(&agg2[(size_t)dst[e] * NCLASS + c],
              ew[e] * support2[(size_t)src[e] * NCLASS + c]);
}

// ---------------------------------------------------------------------------
// Kernel 5: out = log_softmax(agg2 + b2, axis=1)    (16 classes, 1 thread/node)
// ---------------------------------------------------------------------------
__global__ __launch_bounds__(256) void k_lsm(const float* __restrict__ agg2,
                                             const float* __restrict__ b2,
                                             float* __restrict__ out) {
    const int n = blockIdx.x * 256 + threadIdx.x;
    if (n >= N_NODES) return;
    float v[NCLASS];
    float m = -1e30f;
#pragma unroll
    for (int c = 0; c < NCLASS; ++c) {
        v[c] = agg2[(size_t)n * NCLASS + c] + b2[c];
        m = fmaxf(m, v[c]);
    }
    float s = 0.f;
#pragma unroll
    for (int c = 0; c < NCLASS; ++c) s += __expf(v[c] - m);
    const float lse = m + __logf(s);
#pragma unroll
    for (int c = 0; c < NCLASS; ++c) out[(size_t)n * NCLASS + c] = v[c] - lse;
}

extern "C" void kernel_launch(void* const* d_in, const int* in_sizes, int n_in,
                              void* d_out, int out_size, void* d_ws, size_t ws_size,
                              hipStream_t stream) {
    const float* x   = (const float*)d_in[0];
    const int*   src = (const int*)d_in[1];
    const int*   dst = (const int*)d_in[2];
    const float* ew  = (const float*)d_in[3];
    const float* W1  = (const float*)d_in[4];
    const float* b1  = (const float*)d_in[5];
    const float* W2  = (const float*)d_in[6];
    const float* b2  = (const float*)d_in[7];
    float* out = (float*)d_out;

    // workspace layout (floats): support1[N*64] | agg1[N*64] | support2[N*16] | agg2[N*16]
    float* support1 = (float*)d_ws;
    float* agg1     = support1 + (size_t)N_NODES * NHID;
    float* support2 = agg1     + (size_t)N_NODES * NHID;
    float* agg2     = support2 + (size_t)N_NODES * NCLASS;

    hipMemsetAsync(agg1, 0, sizeof(float) * (size_t)N_NODES * NHID, stream);
    hipMemsetAsync(agg2, 0, sizeof(float) * (size_t)N_NODES * NCLASS, stream);

    k_gemm1<<<(N_NODES + 3) / 4, 256, 0, stream>>>(x, W1, support1);
    k_scatter1<<<(N_EDGES + 3) / 4, 256, 0, stream>>>(src, dst, ew, support1, agg1);
    k_gemm2<<<N_NODES / 16, 256, 0, stream>>>(agg1, b1, W2, support2);
    k_scatter2<<<(N_EDGES + 15) / 16, 256, 0, stream>>>(src, dst, ew, support2, agg2);
    k_lsm<<<(N_NODES + 255) / 256, 256, 0, stream>>>(agg2, b2, out);
}

// Round 2
// 585.392 us; speedup vs baseline: 1.1250x; 1.1250x over previous
//
#include <hip/hip_runtime.h>

#define N_NODES 100000
#define N_EDGES 1600000
#define NFEAT 128
#define NHID 64
#define NCLASS 16
#define SCAN_BLOCK 1024
#define NSCAN ((N_NODES + SCAN_BLOCK - 1) / SCAN_BLOCK)   // 98

// ---------------------------------------------------------------------------
// CSR build (per call; harness re-poisons ws every timed launch)
// ---------------------------------------------------------------------------
__global__ __launch_bounds__(256) void k_hist(const int* __restrict__ dst, int* __restrict__ cnt) {
    int e = blockIdx.x * 256 + threadIdx.x;
    if (e < N_EDGES) atomicAdd(&cnt[dst[e]], 1);
}

// block = 256 threads, 4 nodes/thread -> 1024 nodes/block. Exclusive scan in-block.
__global__ __launch_bounds__(256) void k_scan1(const int* __restrict__ cnt,
                                               int* __restrict__ row_ptr,
                                               int* __restrict__ bsum) {
    __shared__ int ts[256];
    const int base = blockIdx.x * SCAN_BLOCK + threadIdx.x * 4;
    int v[4]; int s = 0;
#pragma unroll
    for (int i = 0; i < 4; ++i) { int n = base + i; v[i] = (n < N_NODES) ? cnt[n] : 0; s += v[i]; }
    ts[threadIdx.x] = s;
    __syncthreads();
    for (int off = 1; off < 256; off <<= 1) {
        int t = (threadIdx.x >= off) ? ts[threadIdx.x - off] : 0;
        __syncthreads();
        ts[threadIdx.x] += t;
        __syncthreads();
    }
    int excl = (threadIdx.x > 0) ? ts[threadIdx.x - 1] : 0;
#pragma unroll
    for (int i = 0; i < 4; ++i) { int n = base + i; if (n < N_NODES) row_ptr[n] = excl; excl += v[i]; }
    if (threadIdx.x == 255) bsum[blockIdx.x] = ts[255];
}

__global__ __launch_bounds__(128) void k_scan2(int* __restrict__ bsum) {
    __shared__ int ts[128];
    int v = (threadIdx.x < NSCAN) ? bsum[threadIdx.x] : 0;
    ts[threadIdx.x] = v;
    __syncthreads();
    for (int off = 1; off < 128; off <<= 1) {
        int t = (threadIdx.x >= off) ? ts[threadIdx.x - off] : 0;
        __syncthreads();
        ts[threadIdx.x] += t;
        __syncthreads();
    }
    if (threadIdx.x < NSCAN) bsum[threadIdx.x] = (threadIdx.x > 0) ? ts[threadIdx.x - 1] : 0;
}

__global__ __launch_bounds__(256) void k_scan3(int* __restrict__ row_ptr,
                                               const int* __restrict__ bsum,
                                               int* __restrict__ fill) {
    int n = blockIdx.x * 256 + threadIdx.x;
    if (n < N_NODES) {
        int r = row_ptr[n] + bsum[n / SCAN_BLOCK];
        row_ptr[n] = r;
        fill[n] = r;
    }
    if (n == 0) row_ptr[N_NODES] = N_EDGES;
}

__global__ __launch_bounds__(256) void k_permute(const int* __restrict__ dst,
                                                 int* __restrict__ fill,
                                                 int* __restrict__ perm) {
    int e = blockIdx.x * 256 + threadIdx.x;
    if (e >= N_EDGES) return;
    int p = atomicAdd(&fill[dst[e]], 1);
    perm[p] = e;
}

// ---------------------------------------------------------------------------
// support1 = x @ W1    [N,128]@[128,64] -> [N,64]
// 16 nodes/block (100000 = 16*6250 exact). Wave w handles 4 nodes, lane j = hid.
// ---------------------------------------------------------------------------
__global__ __launch_bounds__(256) void k_gemm1(const float* __restrict__ x,
                                               const float* __restrict__ W1,
                                               float* __restrict__ support1) {
    __shared__ float xs[16][NFEAT];
    const int node0 = blockIdx.x * 16;
    const float4* x4 = (const float4*)(x + (size_t)node0 * NFEAT);
    float4* xs4 = (float4*)xs;
    for (int i = threadIdx.x; i < 16 * NFEAT / 4; i += 256) xs4[i] = x4[i];
    __syncthreads();

    const int j  = threadIdx.x & 63;
    const int l0 = (threadIdx.x >> 6) * 4;
    float acc0 = 0, acc1 = 0, acc2 = 0, acc3 = 0;
    for (int k = 0; k < NFEAT; k += 4) {
        float w0 = W1[(k + 0) * NHID + j];
        float w1 = W1[(k + 1) * NHID + j];
        float w2 = W1[(k + 2) * NHID + j];
        float w3 = W1[(k + 3) * NHID + j];
        float4 a0 = *(const float4*)&xs[l0 + 0][k];
        float4 a1 = *(const float4*)&xs[l0 + 1][k];
        float4 a2 = *(const float4*)&xs[l0 + 2][k];
        float4 a3 = *(const float4*)&xs[l0 + 3][k];
        acc0 += a0.x * w0 + a0.y * w1 + a0.z * w2 + a0.w * w3;
        acc1 += a1.x * w0 + a1.y * w1 + a1.z * w2 + a1.w * w3;
        acc2 += a2.x * w0 + a2.y * w1 + a2.z * w2 + a2.w * w3;
        acc3 += a3.x * w0 + a3.y * w1 + a3.z * w2 + a3.w * w3;
    }
    size_t base = (size_t)(node0 + l0) * NHID + j;
    support1[base]            = acc0;
    support1[base + NHID]     = acc1;
    support1[base + 2 * NHID] = acc2;
    support1[base + 3 * NHID] = acc3;
}

// ---------------------------------------------------------------------------
// h = relu(csr_gather(support1) + b1)   — one wave per dst node, lane j = feat.
// No atomics: each output row written exactly once.
// ---------------------------------------------------------------------------
__global__ __launch_bounds__(256) void k_agg1(const int* __restrict__ row_ptr,
                                              const int* __restrict__ perm,
                                              const int* __restrict__ src,
                                              const float* __restrict__ ew,
                                              const float* __restrict__ support1,
                                              const float* __restrict__ b1,
                                              float* __restrict__ h) {
    const int n = blockIdx.x * 4 + (threadIdx.x >> 6);
    if (n >= N_NODES) return;
    const int j = threadIdx.x & 63;
    const int beg = row_ptr[n], end = row_ptr[n + 1];
    float acc = 0.f;
    int i = beg;
    for (; i + 1 < end; i += 2) {
        int p0 = perm[i], p1 = perm[i + 1];
        int s0 = src[p0], s1 = src[p1];
        float w0 = ew[p0], w1 = ew[p1];
        float v0 = support1[(size_t)s0 * NHID + j];
        float v1 = support1[(size_t)s1 * NHID + j];
        acc += w0 * v0;
        acc += w1 * v1;
    }
    if (i < end) {
        int p = perm[i];
        acc += ew[p] * support1[(size_t)src[p] * NHID + j];
    }
    float v = acc + b1[j];
    h[(size_t)n * NHID + j] = v > 0.f ? v : 0.f;
}

// ---------------------------------------------------------------------------
// support2 = h @ W2    [N,64]@[64,16] -> [N,16]; 16 nodes/block, 1 out/thread.
// ---------------------------------------------------------------------------
__global__ __launch_bounds__(256) void k_gemm2(const float* __restrict__ h,
                                               const float* __restrict__ W2,
                                               float* __restrict__ support2) {
    __shared__ float hs[16][NHID + 1];
    __shared__ float w2s[NHID * NCLASS];
    const int node0 = blockIdx.x * 16;
    for (int i = threadIdx.x; i < NHID * NCLASS; i += 256) w2s[i] = W2[i];
    for (int i = threadIdx.x; i < 16 * NHID; i += 256)
        hs[i >> 6][i & 63] = h[(size_t)node0 * NHID + i];
    __syncthreads();

    const int l = threadIdx.x >> 4;
    const int c = threadIdx.x & 15;
    float acc = 0.f;
#pragma unroll
    for (int k = 0; k < NHID; ++k) acc += hs[l][k] * w2s[k * NCLASS + c];
    support2[(size_t)(node0 + l) * NCLASS + c] = acc;
}

// ---------------------------------------------------------------------------
// out = log_softmax(csr_gather(support2) + b2)  — 16 lanes/node, fused epilogue.
// ---------------------------------------------------------------------------
__global__ __launch_bounds__(256) void k_agg2lsm(const int* __restrict__ row_ptr,
                                                 const int* __restrict__ perm,
                                                 const int* __restrict__ src,
                                                 const float* __restrict__ ew,
                                                 const float* __restrict__ support2,
                                                 const float* __restrict__ b2,
                                                 float* __restrict__ out) {
    const int n = blockIdx.x * 16 + (threadIdx.x >> 4);
    if (n >= N_NODES) return;
    const int c = threadIdx.x & 15;
    const int beg = row_ptr[n], end = row_ptr[n + 1];
    float acc = 0.f;
    int i = beg;
    for (; i + 1 < end; i += 2) {
        int p0 = perm[i], p1 = perm[i + 1];
        acc += ew[p0] * support2[(size_t)src[p0] * NCLASS + c];
        acc += ew[p1] * support2[(size_t)src[p1] * NCLASS + c];
    }
    if (i < end) {
        int p = perm[i];
        acc += ew[p] * support2[(size_t)src[p] * NCLASS + c];
    }
    float v = acc + b2[c];
    float m = v;
#pragma unroll
    for (int off = 8; off >= 1; off >>= 1) m = fmaxf(m, __shfl_xor(m, off, 16));
    float s = __expf(v - m);
#pragma unroll
    for (int off = 8; off >= 1; off >>= 1) s += __shfl_xor(s, off, 16);
    out[(size_t)n * NCLASS + c] = v - m - __logf(s);
}

extern "C" void kernel_launch(void* const* d_in, const int* in_sizes, int n_in,
                              void* d_out, int out_size, void* d_ws, size_t ws_size,
                              hipStream_t stream) {
    const float* x   = (const float*)d_in[0];
    const int*   src = (const int*)d_in[1];
    const int*   dst = (const int*)d_in[2];
    const float* ew  = (const float*)d_in[3];
    const float* W1  = (const float*)d_in[4];
    const float* b1  = (const float*)d_in[5];
    const float* W2  = (const float*)d_in[6];
    const float* b2  = (const float*)d_in[7];
    float* out = (float*)d_out;

    // ws layout (4-byte units), total ~59.2 MB (<= 64 MB proven available):
    // support1[N*64] | h[N*64] | perm[E] | row_ptr[N+1] | cnt[N] | fill[N] | bsum[128]
    // support2 aliases support1 (dead after k_agg1).
    float* support1 = (float*)d_ws;
    float* h        = support1 + (size_t)N_NODES * NHID;
    int*   perm     = (int*)(h + (size_t)N_NODES * NHID);
    int*   row_ptr  = perm + N_EDGES;
    int*   cnt      = row_ptr + (N_NODES + 1);
    int*   fill     = cnt + N_NODES;
    int*   bsum     = fill + N_NODES;
    float* support2 = support1;   // alias: support1 dead after k_agg1

    hipMemsetAsync(cnt, 0, sizeof(int) * N_NODES, stream);

    // CSR build (shared by both layers — same dst)
    k_hist   <<<(N_EDGES + 255) / 256, 256, 0, stream>>>(dst, cnt);
    k_scan1  <<<NSCAN, 256, 0, stream>>>(cnt, row_ptr, bsum);
    k_scan2  <<<1, 128, 0, stream>>>(bsum);
    k_scan3  <<<(N_NODES + 255) / 256, 256, 0, stream>>>(row_ptr, bsum, fill);
    k_permute<<<(N_EDGES + 255) / 256, 256, 0, stream>>>(dst, fill, perm);

    // layer 1
    k_gemm1<<<N_NODES / 16, 256, 0, stream>>>(x, W1, support1);
    k_agg1 <<<(N_NODES + 3) / 4, 256, 0, stream>>>(row_ptr, perm, src, ew, support1, b1, h);

    // layer 2 + log_softmax
    k_gemm2  <<<N_NODES / 16, 256, 0, stream>>>(h, W2, support2);
    k_agg2lsm<<<(N_NODES + 15) / 16, 256, 0, stream>>>(row_ptr, perm, src, ew, support2, b2, out);
}

// Round 3
// 436.838 us; speedup vs baseline: 1.5075x; 1.3401x over previous
//
#include <hip/hip_runtime.h>

#define N_NODES 100000
#define N_EDGES 1600000
#define NFEAT 128
#define NHID 64
#define NCLASS 16
#define SCAN_BLOCK 1024
#define NSCAN ((N_NODES + SCAN_BLOCK - 1) / SCAN_BLOCK)   // 98

__device__ __forceinline__ float bf2f(unsigned short u) {
    return __uint_as_float(((unsigned int)u) << 16);
}
__device__ __forceinline__ unsigned short f2bf(float f) {
    unsigned int b = __float_as_uint(f);
    b += 0x7FFFu + ((b >> 16) & 1u);   // RNE
    return (unsigned short)(b >> 16);
}

// ---------------------------------------------------------------------------
// CSR build (per call; ws re-poisoned each timed launch)
// ---------------------------------------------------------------------------
__global__ __launch_bounds__(256) void k_hist(const int* __restrict__ dst, int* __restrict__ cnt) {
    int e = blockIdx.x * 256 + threadIdx.x;
    if (e < N_EDGES) atomicAdd(&cnt[dst[e]], 1);
}

__global__ __launch_bounds__(256) void k_scan1(const int* __restrict__ cnt,
                                               int* __restrict__ row_ptr,
                                               int* __restrict__ bsum) {
    __shared__ int ts[256];
    const int base = blockIdx.x * SCAN_BLOCK + threadIdx.x * 4;
    int v[4]; int s = 0;
#pragma unroll
    for (int i = 0; i < 4; ++i) { int n = base + i; v[i] = (n < N_NODES) ? cnt[n] : 0; s += v[i]; }
    ts[threadIdx.x] = s;
    __syncthreads();
    for (int off = 1; off < 256; off <<= 1) {
        int t = (threadIdx.x >= off) ? ts[threadIdx.x - off] : 0;
        __syncthreads();
        ts[threadIdx.x] += t;
        __syncthreads();
    }
    int excl = (threadIdx.x > 0) ? ts[threadIdx.x - 1] : 0;
#pragma unroll
    for (int i = 0; i < 4; ++i) { int n = base + i; if (n < N_NODES) row_ptr[n] = excl; excl += v[i]; }
    if (threadIdx.x == 255) bsum[blockIdx.x] = ts[255];
}

__global__ __launch_bounds__(128) void k_scan2(int* __restrict__ bsum) {
    __shared__ int ts[128];
    int v = (threadIdx.x < NSCAN) ? bsum[threadIdx.x] : 0;
    ts[threadIdx.x] = v;
    __syncthreads();
    for (int off = 1; off < 128; off <<= 1) {
        int t = (threadIdx.x >= off) ? ts[threadIdx.x - off] : 0;
        __syncthreads();
        ts[threadIdx.x] += t;
        __syncthreads();
    }
    if (threadIdx.x < NSCAN) bsum[threadIdx.x] = (threadIdx.x > 0) ? ts[threadIdx.x - 1] : 0;
}

__global__ __launch_bounds__(256) void k_scan3(int* __restrict__ row_ptr,
                                               const int* __restrict__ bsum,
                                               int* __restrict__ fill) {
    int n = blockIdx.x * 256 + threadIdx.x;
    if (n < N_NODES) {
        int r = row_ptr[n] + bsum[n / SCAN_BLOCK];
        row_ptr[n] = r;
        fill[n] = r;
    }
    if (n == 0) row_ptr[N_NODES] = N_EDGES;
}

// writes sorted (src, weight) pairs: removes one indirection from agg loops
__global__ __launch_bounds__(256) void k_permute(const int* __restrict__ dst,
                                                 const int* __restrict__ src,
                                                 const float* __restrict__ ew,
                                                 int* __restrict__ fill,
                                                 int2* __restrict__ edge2) {
    int e = blockIdx.x * 256 + threadIdx.x;
    if (e >= N_EDGES) return;
    int p = atomicAdd(&fill[dst[e]], 1);
    edge2[p] = make_int2(src[e], __float_as_int(ew[e]));
}

// ---------------------------------------------------------------------------
// support1 = bf16(x @ W1)    [N,128]@[128,64] -> [N,64]
// ---------------------------------------------------------------------------
__global__ __launch_bounds__(256) void k_gemm1(const float* __restrict__ x,
                                               const float* __restrict__ W1,
                                               unsigned short* __restrict__ s1) {
    __shared__ float xs[16][NFEAT];
    const int node0 = blockIdx.x * 16;
    const float4* x4 = (const float4*)(x + (size_t)node0 * NFEAT);
    float4* xs4 = (float4*)xs;
    for (int i = threadIdx.x; i < 16 * NFEAT / 4; i += 256) xs4[i] = x4[i];
    __syncthreads();

    const int j  = threadIdx.x & 63;
    const int l0 = (threadIdx.x >> 6) * 4;
    float acc0 = 0, acc1 = 0, acc2 = 0, acc3 = 0;
    for (int k = 0; k < NFEAT; k += 4) {
        float w0 = W1[(k + 0) * NHID + j];
        float w1 = W1[(k + 1) * NHID + j];
        float w2 = W1[(k + 2) * NHID + j];
        float w3 = W1[(k + 3) * NHID + j];
        float4 a0 = *(const float4*)&xs[l0 + 0][k];
        float4 a1 = *(const float4*)&xs[l0 + 1][k];
        float4 a2 = *(const float4*)&xs[l0 + 2][k];
        float4 a3 = *(const float4*)&xs[l0 + 3][k];
        acc0 += a0.x * w0 + a0.y * w1 + a0.z * w2 + a0.w * w3;
        acc1 += a1.x * w0 + a1.y * w1 + a1.z * w2 + a1.w * w3;
        acc2 += a2.x * w0 + a2.y * w1 + a2.z * w2 + a2.w * w3;
        acc3 += a3.x * w0 + a3.y * w1 + a3.z * w2 + a3.w * w3;
    }
    size_t base = (size_t)(node0 + l0) * NHID + j;
    s1[base]            = f2bf(acc0);
    s1[base + NHID]     = f2bf(acc1);
    s1[base + 2 * NHID] = f2bf(acc2);
    s1[base + 3 * NHID] = f2bf(acc3);
}

// ---------------------------------------------------------------------------
// Fused: h = relu(gather(s1) + b1);  s2 = bf16(h @ W2)
// 4 nodes/block (one wave each, lane j = hid feat); gemm2 tail via LDS.
// ---------------------------------------------------------------------------
__global__ __launch_bounds__(256) void k_agg1g2(const int* __restrict__ row_ptr,
                                                const int2* __restrict__ edge2,
                                                const unsigned short* __restrict__ s1,
                                                const float* __restrict__ b1,
                                                const float* __restrict__ W2,
                                                unsigned short* __restrict__ s2) {
    __shared__ float hs[4][NHID + 1];
    __shared__ float w2s[NHID * NCLASS];
    for (int i = threadIdx.x; i < NHID * NCLASS; i += 256) w2s[i] = W2[i];

    const int n = blockIdx.x * 4 + (threadIdx.x >> 6);
    const int j = threadIdx.x & 63;
    const int beg = row_ptr[n], end = row_ptr[n + 1];
    float acc = 0.f;
    int i = beg;
    for (; i + 4 <= end; i += 4) {
        int2 e0 = edge2[i], e1 = edge2[i + 1], e2 = edge2[i + 2], e3 = edge2[i + 3];
        float v0 = bf2f(s1[(size_t)e0.x * NHID + j]);
        float v1 = bf2f(s1[(size_t)e1.x * NHID + j]);
        float v2 = bf2f(s1[(size_t)e2.x * NHID + j]);
        float v3 = bf2f(s1[(size_t)e3.x * NHID + j]);
        acc += __int_as_float(e0.y) * v0;
        acc += __int_as_float(e1.y) * v1;
        acc += __int_as_float(e2.y) * v2;
        acc += __int_as_float(e3.y) * v3;
    }
    for (; i < end; ++i) {
        int2 e = edge2[i];
        acc += __int_as_float(e.y) * bf2f(s1[(size_t)e.x * NHID + j]);
    }
    float v = acc + b1[j];
    hs[threadIdx.x >> 6][j] = v > 0.f ? v : 0.f;
    __syncthreads();

    // gemm2 tail: 64 threads compute 4 nodes x 16 classes
    if (threadIdx.x < 64) {
        const int l = threadIdx.x >> 4;
        const int c = threadIdx.x & 15;
        float a = 0.f;
#pragma unroll
        for (int k = 0; k < NHID; ++k) a += hs[l][k] * w2s[k * NCLASS + c];
        s2[(size_t)(blockIdx.x * 4 + l) * NCLASS + c] = f2bf(a);
    }
}

// ---------------------------------------------------------------------------
// out = log_softmax(gather(s2) + b2)  — 16 lanes/node; s2 is 3.2 MB (L2-warm)
// ---------------------------------------------------------------------------
__global__ __launch_bounds__(256) void k_agg2lsm(const int* __restrict__ row_ptr,
                                                 const int2* __restrict__ edge2,
                                                 const unsigned short* __restrict__ s2,
                                                 const float* __restrict__ b2,
                                                 float* __restrict__ out) {
    const int n = blockIdx.x * 16 + (threadIdx.x >> 4);
    const int c = threadIdx.x & 15;
    const int beg = row_ptr[n], end = row_ptr[n + 1];
    float acc = 0.f;
    int i = beg;
    for (; i + 4 <= end; i += 4) {
        int2 e0 = edge2[i], e1 = edge2[i + 1], e2 = edge2[i + 2], e3 = edge2[i + 3];
        float v0 = bf2f(s2[(size_t)e0.x * NCLASS + c]);
        float v1 = bf2f(s2[(size_t)e1.x * NCLASS + c]);
        float v2 = bf2f(s2[(size_t)e2.x * NCLASS + c]);
        float v3 = bf2f(s2[(size_t)e3.x * NCLASS + c]);
        acc += __int_as_float(e0.y) * v0;
        acc += __int_as_float(e1.y) * v1;
        acc += __int_as_float(e2.y) * v2;
        acc += __int_as_float(e3.y) * v3;
    }
    for (; i < end; ++i) {
        int2 e = edge2[i];
        acc += __int_as_float(e.y) * bf2f(s2[(size_t)e.x * NCLASS + c]);
    }
    float v = acc + b2[c];
    float m = v;
#pragma unroll
    for (int off = 8; off >= 1; off >>= 1) m = fmaxf(m, __shfl_xor(m, off, 16));
    float s = __expf(v - m);
#pragma unroll
    for (int off = 8; off >= 1; off >>= 1) s += __shfl_xor(s, off, 16);
    out[(size_t)n * NCLASS + c] = v - m - __logf(s);
}

extern "C" void kernel_launch(void* const* d_in, const int* in_sizes, int n_in,
                              void* d_out, int out_size, void* d_ws, size_t ws_size,
                              hipStream_t stream) {
    const float* x   = (const float*)d_in[0];
    const int*   src = (const int*)d_in[1];
    const int*   dst = (const int*)d_in[2];
    const float* ew  = (const float*)d_in[3];
    const float* W1  = (const float*)d_in[4];
    const float* b1  = (const float*)d_in[5];
    const float* W2  = (const float*)d_in[6];
    const float* b2  = (const float*)d_in[7];
    float* out = (float*)d_out;

    // ws layout: s1 bf16 [N*64] | s2 bf16 [N*16] | edge2 int2 [E] |
    //            row_ptr [N+1] | cnt [N] | fill [N] | bsum [128]   ≈ 30 MB
    unsigned short* s1 = (unsigned short*)d_ws;
    unsigned short* s2 = s1 + (size_t)N_NODES * NHID;
    int2* edge2        = (int2*)(s2 + (size_t)N_NODES * NCLASS);
    int*  row_ptr      = (int*)(edge2 + N_EDGES);
    int*  cnt          = row_ptr + (N_NODES + 1);
    int*  fill         = cnt + N_NODES;
    int*  bsum         = fill + N_NODES;

    hipMemsetAsync(cnt, 0, sizeof(int) * N_NODES, stream);

    k_hist   <<<(N_EDGES + 255) / 256, 256, 0, stream>>>(dst, cnt);
    k_scan1  <<<NSCAN, 256, 0, stream>>>(cnt, row_ptr, bsum);
    k_scan2  <<<1, 128, 0, stream>>>(bsum);
    k_scan3  <<<(N_NODES + 255) / 256, 256, 0, stream>>>(row_ptr, bsum, fill);
    k_permute<<<(N_EDGES + 255) / 256, 256, 0, stream>>>(dst, src, ew, fill, edge2);

    k_gemm1  <<<N_NODES / 16, 256, 0, stream>>>(x, W1, s1);
    k_agg1g2 <<<N_NODES / 4, 256, 0, stream>>>(row_ptr, edge2, s1, b1, W2, s2);
    k_agg2lsm<<<N_NODES / 16, 256, 0, stream>>>(row_ptr, edge2, s2, b2, out);
}

// Round 4
// 331.308 us; speedup vs baseline: 1.9877x; 1.3185x over previous
//
#include <hip/hip_runtime.h>

#define N_NODES 100000
#define N_EDGES 1600000
#define NFEAT 128
#define NHID 64
#define NCLASS 16

#define BSHIFT 9                                   // 512 nodes per bucket
#define BUCK_NODES 512
#define NBUCK ((N_NODES + BUCK_NODES - 1) >> BSHIFT)   // 196
#define EDGE_TILE 8192
#define NB_SCAT ((N_EDGES + EDGE_TILE - 1) / EDGE_TILE) // 196

__device__ __forceinline__ float bf2f(unsigned short u) {
    return __uint_as_float(((unsigned int)u) << 16);
}
__device__ __forceinline__ unsigned short f2bf(float f) {
    unsigned int b = __float_as_uint(f);
    b += 0x7FFFu + ((b >> 16) & 1u);   // RNE
    return (unsigned short)(b >> 16);
}

// ---------------------------------------------------------------------------
// Sort phase 1a: bucket histogram (LDS-local, one global atomic per bucket/blk)
// ---------------------------------------------------------------------------
__global__ __launch_bounds__(256) void k_bhist(const int* __restrict__ dst,
                                               int* __restrict__ bucket_cnt) {
    __shared__ int hist[NBUCK];
    for (int i = threadIdx.x; i < NBUCK; i += 256) hist[i] = 0;
    __syncthreads();
    const int base = blockIdx.x * EDGE_TILE;
    for (int i = threadIdx.x; i < EDGE_TILE; i += 256) {
        int e = base + i;
        if (e < N_EDGES) atomicAdd(&hist[dst[e] >> BSHIFT], 1);
    }
    __syncthreads();
    for (int i = threadIdx.x; i < NBUCK; i += 256)
        if (hist[i]) atomicAdd(&bucket_cnt[i], hist[i]);
}

// ---------------------------------------------------------------------------
// Sort phase 1b: exclusive scan of 196 bucket counts (single block)
// ---------------------------------------------------------------------------
__global__ __launch_bounds__(256) void k_bscan(const int* __restrict__ bucket_cnt,
                                               int* __restrict__ bucket_ptr,
                                               int* __restrict__ fill,
                                               int* __restrict__ row_ptr) {
    __shared__ int ts[256];
    int v = (threadIdx.x < NBUCK) ? bucket_cnt[threadIdx.x] : 0;
    ts[threadIdx.x] = v;
    __syncthreads();
    for (int off = 1; off < 256; off <<= 1) {
        int t = (threadIdx.x >= off) ? ts[threadIdx.x - off] : 0;
        __syncthreads();
        ts[threadIdx.x] += t;
        __syncthreads();
    }
    int excl = threadIdx.x ? ts[threadIdx.x - 1] : 0;
    if (threadIdx.x < NBUCK) { bucket_ptr[threadIdx.x] = excl; fill[threadIdx.x] = excl; }
    if (threadIdx.x == 0) { bucket_ptr[NBUCK] = N_EDGES; row_ptr[N_NODES] = N_EDGES; }
}

// ---------------------------------------------------------------------------
// Sort phase 2: bucket-scatter. Per-block LDS hist -> one global atomic per
// bucket reserves a contiguous run -> writes are ~42-edge (336 B) bursts.
// Record packs (src 17b | local_dst 9b) + fp32 weight.
// ---------------------------------------------------------------------------
__global__ __launch_bounds__(256) void k_bscatter(const int* __restrict__ dst,
                                                  const int* __restrict__ src,
                                                  const float* __restrict__ ew,
                                                  int* __restrict__ fill,
                                                  int2* __restrict__ edgeA) {
    __shared__ int hist[NBUCK], bbase[NBUCK], bfill[NBUCK];
    for (int i = threadIdx.x; i < NBUCK; i += 256) { hist[i] = 0; bfill[i] = 0; }
    __syncthreads();
    const int base = blockIdx.x * EDGE_TILE;
    for (int i = threadIdx.x; i < EDGE_TILE; i += 256) {
        int e = base + i;
        if (e < N_EDGES) atomicAdd(&hist[dst[e] >> BSHIFT], 1);
    }
    __syncthreads();
    for (int i = threadIdx.x; i < NBUCK; i += 256)
        bbase[i] = hist[i] ? atomicAdd(&fill[i], hist[i]) : 0;
    __syncthreads();
    for (int i = threadIdx.x; i < EDGE_TILE; i += 256) {
        int e = base + i;
        if (e >= N_EDGES) break;
        int d = dst[e];
        int b = d >> BSHIFT;
        int r = atomicAdd(&bfill[b], 1);
        edgeA[bbase[b] + r] = make_int2(src[e] | ((d & (BUCK_NODES - 1)) << 17),
                                        __float_as_int(ew[e]));
    }
}

// ---------------------------------------------------------------------------
// Sort phase 3: in-bucket exact sort by dst. One block per bucket; exact LDS
// histogram + scan emits row_ptr; scatter stays inside a 64 KB window (L2).
// Output record: (src, weight).
// ---------------------------------------------------------------------------
__global__ __launch_bounds__(256) void k_bsort(const int* __restrict__ bucket_ptr,
                                               const int2* __restrict__ edgeA,
                                               int2* __restrict__ edgeB,
                                               int* __restrict__ row_ptr) {
    __shared__ int hist[BUCK_NODES], rstart[BUCK_NODES], lfill[BUCK_NODES];
    __shared__ int ts[256];
    const int b = blockIdx.x;
    const int beg = bucket_ptr[b], end = bucket_ptr[b + 1];
    for (int i = threadIdx.x; i < BUCK_NODES; i += 256) { hist[i] = 0; lfill[i] = 0; }
    __syncthreads();
    for (int p = beg + threadIdx.x; p < end; p += 256)
        atomicAdd(&hist[edgeA[p].x >> 17], 1);
    __syncthreads();
    // exclusive scan over 512 entries (2 per thread)
    int a0 = hist[threadIdx.x * 2], a1 = hist[threadIdx.x * 2 + 1];
    ts[threadIdx.x] = a0 + a1;
    __syncthreads();
    for (int off = 1; off < 256; off <<= 1) {
        int t = (threadIdx.x >= off) ? ts[threadIdx.x - off] : 0;
        __syncthreads();
        ts[threadIdx.x] += t;
        __syncthreads();
    }
    int excl = threadIdx.x ? ts[threadIdx.x - 1] : 0;
    rstart[threadIdx.x * 2]     = excl;
    rstart[threadIdx.x * 2 + 1] = excl + a0;
    __syncthreads();
    const int node0 = b << BSHIFT;
    for (int i = threadIdx.x; i < BUCK_NODES; i += 256) {
        int n = node0 + i;
        if (n < N_NODES) row_ptr[n] = beg + rstart[i];
    }
    for (int p = beg + threadIdx.x; p < end; p += 256) {
        int2 e = edgeA[p];
        int ld = e.x >> 17;
        int r = atomicAdd(&lfill[ld], 1);
        edgeB[beg + rstart[ld] + r] = make_int2(e.x & 0x1FFFF, e.y);
    }
}

// ---------------------------------------------------------------------------
// support1 = bf16(x @ W1)    [N,128]@[128,64] -> [N,64]
// ---------------------------------------------------------------------------
__global__ __launch_bounds__(256) void k_gemm1(const float* __restrict__ x,
                                               const float* __restrict__ W1,
                                               unsigned short* __restrict__ s1) {
    __shared__ float xs[16][NFEAT];
    const int node0 = blockIdx.x * 16;
    const float4* x4 = (const float4*)(x + (size_t)node0 * NFEAT);
    float4* xs4 = (float4*)xs;
    for (int i = threadIdx.x; i < 16 * NFEAT / 4; i += 256) xs4[i] = x4[i];
    __syncthreads();

    const int j  = threadIdx.x & 63;
    const int l0 = (threadIdx.x >> 6) * 4;
    float acc0 = 0, acc1 = 0, acc2 = 0, acc3 = 0;
    for (int k = 0; k < NFEAT; k += 4) {
        float w0 = W1[(k + 0) * NHID + j];
        float w1 = W1[(k + 1) * NHID + j];
        float w2 = W1[(k + 2) * NHID + j];
        float w3 = W1[(k + 3) * NHID + j];
        float4 a0 = *(const float4*)&xs[l0 + 0][k];
        float4 a1 = *(const float4*)&xs[l0 + 1][k];
        float4 a2 = *(const float4*)&xs[l0 + 2][k];
        float4 a3 = *(const float4*)&xs[l0 + 3][k];
        acc0 += a0.x * w0 + a0.y * w1 + a0.z * w2 + a0.w * w3;
        acc1 += a1.x * w0 + a1.y * w1 + a1.z * w2 + a1.w * w3;
        acc2 += a2.x * w0 + a2.y * w1 + a2.z * w2 + a2.w * w3;
        acc3 += a3.x * w0 + a3.y * w1 + a3.z * w2 + a3.w * w3;
    }
    size_t base = (size_t)(node0 + l0) * NHID + j;
    s1[base]            = f2bf(acc0);
    s1[base + NHID]     = f2bf(acc1);
    s1[base + 2 * NHID] = f2bf(acc2);
    s1[base + 3 * NHID] = f2bf(acc3);
}

// ---------------------------------------------------------------------------
// Fused: h = relu(gather(s1) + b1);  s2 = bf16(h @ W2)
// ---------------------------------------------------------------------------
__global__ __launch_bounds__(256) void k_agg1g2(const int* __restrict__ row_ptr,
                                                const int2* __restrict__ edge2,
                                                const unsigned short* __restrict__ s1,
                                                const float* __restrict__ b1,
                                                const float* __restrict__ W2,
                                                unsigned short* __restrict__ s2) {
    __shared__ float hs[4][NHID + 1];
    __shared__ float w2s[NHID * NCLASS];
    for (int i = threadIdx.x; i < NHID * NCLASS; i += 256) w2s[i] = W2[i];

    const int n = blockIdx.x * 4 + (threadIdx.x >> 6);
    const int j = threadIdx.x & 63;
    const int beg = row_ptr[n], end = row_ptr[n + 1];
    float acc = 0.f;
    int i = beg;
    for (; i + 4 <= end; i += 4) {
        int2 e0 = edge2[i], e1 = edge2[i + 1], e2 = edge2[i + 2], e3 = edge2[i + 3];
        float v0 = bf2f(s1[(size_t)e0.x * NHID + j]);
        float v1 = bf2f(s1[(size_t)e1.x * NHID + j]);
        float v2 = bf2f(s1[(size_t)e2.x * NHID + j]);
        float v3 = bf2f(s1[(size_t)e3.x * NHID + j]);
        acc += __int_as_float(e0.y) * v0;
        acc += __int_as_float(e1.y) * v1;
        acc += __int_as_float(e2.y) * v2;
        acc += __int_as_float(e3.y) * v3;
    }
    for (; i < end; ++i) {
        int2 e = edge2[i];
        acc += __int_as_float(e.y) * bf2f(s1[(size_t)e.x * NHID + j]);
    }
    float v = acc + b1[j];
    hs[threadIdx.x >> 6][j] = v > 0.f ? v : 0.f;
    __syncthreads();

    if (threadIdx.x < 64) {
        const int l = threadIdx.x >> 4;
        const int c = threadIdx.x & 15;
        float a = 0.f;
#pragma unroll
        for (int k = 0; k < NHID; ++k) a += hs[l][k] * w2s[k * NCLASS + c];
        s2[(size_t)(blockIdx.x * 4 + l) * NCLASS + c] = f2bf(a);
    }
}

// ---------------------------------------------------------------------------
// out = log_softmax(gather(s2) + b2)
// ---------------------------------------------------------------------------
__global__ __launch_bounds__(256) void k_agg2lsm(const int* __restrict__ row_ptr,
                                                 const int2* __restrict__ edge2,
                                                 const unsigned short* __restrict__ s2,
                                                 const float* __restrict__ b2,
                                                 float* __restrict__ out) {
    const int n = blockIdx.x * 16 + (threadIdx.x >> 4);
    const int c = threadIdx.x & 15;
    const int beg = row_ptr[n], end = row_ptr[n + 1];
    float acc = 0.f;
    int i = beg;
    for (; i + 4 <= end; i += 4) {
        int2 e0 = edge2[i], e1 = edge2[i + 1], e2 = edge2[i + 2], e3 = edge2[i + 3];
        acc += __int_as_float(e0.y) * bf2f(s2[(size_t)e0.x * NCLASS + c]);
        acc += __int_as_float(e1.y) * bf2f(s2[(size_t)e1.x * NCLASS + c]);
        acc += __int_as_float(e2.y) * bf2f(s2[(size_t)e2.x * NCLASS + c]);
        acc += __int_as_float(e3.y) * bf2f(s2[(size_t)e3.x * NCLASS + c]);
    }
    for (; i < end; ++i) {
        int2 e = edge2[i];
        acc += __int_as_float(e.y) * bf2f(s2[(size_t)e.x * NCLASS + c]);
    }
    float v = acc + b2[c];
    float m = v;
#pragma unroll
    for (int off = 8; off >= 1; off >>= 1) m = fmaxf(m, __shfl_xor(m, off, 16));
    float s = __expf(v - m);
#pragma unroll
    for (int off = 8; off >= 1; off >>= 1) s += __shfl_xor(s, off, 16);
    out[(size_t)n * NCLASS + c] = v - m - __logf(s);
}

extern "C" void kernel_launch(void* const* d_in, const int* in_sizes, int n_in,
                              void* d_out, int out_size, void* d_ws, size_t ws_size,
                              hipStream_t stream) {
    const float* x   = (const float*)d_in[0];
    const int*   src = (const int*)d_in[1];
    const int*   dst = (const int*)d_in[2];
    const float* ew  = (const float*)d_in[3];
    const float* W1  = (const float*)d_in[4];
    const float* b1  = (const float*)d_in[5];
    const float* W2  = (const float*)d_in[6];
    const float* b2  = (const float*)d_in[7];
    float* out = (float*)d_out;

    // ws layout (~42.3 MB): s1 bf16[N*64] | s2 bf16[N*16] | edgeA int2[E] |
    // edgeB int2[E] | row_ptr[N+1] | bucket_cnt[196] | bucket_ptr[197] | fill[196]
    unsigned short* s1 = (unsigned short*)d_ws;
    unsigned short* s2 = s1 + (size_t)N_NODES * NHID;
    int2* edgeA        = (int2*)(s2 + (size_t)N_NODES * NCLASS);
    int2* edgeB        = edgeA + N_EDGES;
    int*  row_ptr      = (int*)(edgeB + N_EDGES);
    int*  bucket_cnt   = row_ptr + (N_NODES + 1);
    int*  bucket_ptr   = bucket_cnt + NBUCK;
    int*  fill         = bucket_ptr + (NBUCK + 1);

    hipMemsetAsync(bucket_cnt, 0, sizeof(int) * NBUCK, stream);

    k_bhist   <<<NB_SCAT, 256, 0, stream>>>(dst, bucket_cnt);
    k_bscan   <<<1, 256, 0, stream>>>(bucket_cnt, bucket_ptr, fill, row_ptr);
    k_bscatter<<<NB_SCAT, 256, 0, stream>>>(dst, src, ew, fill, edgeA);
    k_bsort   <<<NBUCK, 256, 0, stream>>>(bucket_ptr, edgeA, edgeB, row_ptr);

    k_gemm1  <<<N_NODES / 16, 256, 0, stream>>>(x, W1, s1);
    k_agg1g2 <<<N_NODES / 4, 256, 0, stream>>>(row_ptr, edgeB, s1, b1, W2, s2);
    k_agg2lsm<<<N_NODES / 16, 256, 0, stream>>>(row_ptr, edgeB, s2, b2, out);
}

// Round 5
// 321.530 us; speedup vs baseline: 2.0482x; 1.0304x over previous
//
#include <hip/hip_runtime.h>

#define N_NODES 100000
#define N_EDGES 1600000
#define NFEAT 128
#define NHID 64
#define NCLASS 16

#define BSHIFT 9                                   // 512 nodes per bucket
#define BUCK_NODES 512
#define NBUCK ((N_NODES + BUCK_NODES - 1) >> BSHIFT)   // 196
#define EDGE_TILE 8192
#define NB_SCAT ((N_EDGES + EDGE_TILE - 1) / EDGE_TILE) // 196

__device__ __forceinline__ float bf2f(unsigned short u) {
    return __uint_as_float(((unsigned int)u) << 16);
}
__device__ __forceinline__ float bflo(unsigned int u) {
    return __uint_as_float(u << 16);
}
__device__ __forceinline__ float bfhi(unsigned int u) {
    return __uint_as_float(u & 0xFFFF0000u);
}
__device__ __forceinline__ unsigned short f2bf(float f) {
    unsigned int b = __float_as_uint(f);
    b += 0x7FFFu + ((b >> 16) & 1u);   // RNE
    return (unsigned short)(b >> 16);
}

// ---------------------------------------------------------------------------
// Sort phase 1a: bucket histogram
// ---------------------------------------------------------------------------
__global__ __launch_bounds__(256) void k_bhist(const int* __restrict__ dst,
                                               int* __restrict__ bucket_cnt) {
    __shared__ int hist[NBUCK];
    for (int i = threadIdx.x; i < NBUCK; i += 256) hist[i] = 0;
    __syncthreads();
    const int base = blockIdx.x * EDGE_TILE;
    for (int i = threadIdx.x; i < EDGE_TILE; i += 256) {
        int e = base + i;
        if (e < N_EDGES) atomicAdd(&hist[dst[e] >> BSHIFT], 1);
    }
    __syncthreads();
    for (int i = threadIdx.x; i < NBUCK; i += 256)
        if (hist[i]) atomicAdd(&bucket_cnt[i], hist[i]);
}

// ---------------------------------------------------------------------------
// Sort phase 1b: exclusive scan of 196 bucket counts (single block)
// ---------------------------------------------------------------------------
__global__ __launch_bounds__(256) void k_bscan(const int* __restrict__ bucket_cnt,
                                               int* __restrict__ bucket_ptr,
                                               int* __restrict__ fill,
                                               int* __restrict__ row_ptr) {
    __shared__ int ts[256];
    int v = (threadIdx.x < NBUCK) ? bucket_cnt[threadIdx.x] : 0;
    ts[threadIdx.x] = v;
    __syncthreads();
    for (int off = 1; off < 256; off <<= 1) {
        int t = (threadIdx.x >= off) ? ts[threadIdx.x - off] : 0;
        __syncthreads();
        ts[threadIdx.x] += t;
        __syncthreads();
    }
    int excl = threadIdx.x ? ts[threadIdx.x - 1] : 0;
    if (threadIdx.x < NBUCK) { bucket_ptr[threadIdx.x] = excl; fill[threadIdx.x] = excl; }
    if (threadIdx.x == 0) { bucket_ptr[NBUCK] = N_EDGES; row_ptr[N_NODES] = N_EDGES; }
}

// ---------------------------------------------------------------------------
// Sort phase 2: bucket-scatter into ~336 B contiguous runs
// ---------------------------------------------------------------------------
__global__ __launch_bounds__(256) void k_bscatter(const int* __restrict__ dst,
                                                  const int* __restrict__ src,
                                                  const float* __restrict__ ew,
                                                  int* __restrict__ fill,
                                                  int2* __restrict__ edgeA) {
    __shared__ int hist[NBUCK], bbase[NBUCK], bfill[NBUCK];
    for (int i = threadIdx.x; i < NBUCK; i += 256) { hist[i] = 0; bfill[i] = 0; }
    __syncthreads();
    const int base = blockIdx.x * EDGE_TILE;
    for (int i = threadIdx.x; i < EDGE_TILE; i += 256) {
        int e = base + i;
        if (e < N_EDGES) atomicAdd(&hist[dst[e] >> BSHIFT], 1);
    }
    __syncthreads();
    for (int i = threadIdx.x; i < NBUCK; i += 256)
        bbase[i] = hist[i] ? atomicAdd(&fill[i], hist[i]) : 0;
    __syncthreads();
    for (int i = threadIdx.x; i < EDGE_TILE; i += 256) {
        int e = base + i;
        if (e >= N_EDGES) break;
        int d = dst[e];
        int b = d >> BSHIFT;
        int r = atomicAdd(&bfill[b], 1);
        edgeA[bbase[b] + r] = make_int2(src[e] | ((d & (BUCK_NODES - 1)) << 17),
                                        __float_as_int(ew[e]));
    }
}

// ---------------------------------------------------------------------------
// Sort phase 3: in-bucket exact sort by dst; emits row_ptr
// ---------------------------------------------------------------------------
__global__ __launch_bounds__(256) void k_bsort(const int* __restrict__ bucket_ptr,
                                               const int2* __restrict__ edgeA,
                                               int2* __restrict__ edgeB,
                                               int* __restrict__ row_ptr) {
    __shared__ int hist[BUCK_NODES], rstart[BUCK_NODES], lfill[BUCK_NODES];
    __shared__ int ts[256];
    const int b = blockIdx.x;
    const int beg = bucket_ptr[b], end = bucket_ptr[b + 1];
    for (int i = threadIdx.x; i < BUCK_NODES; i += 256) { hist[i] = 0; lfill[i] = 0; }
    __syncthreads();
    for (int p = beg + threadIdx.x; p < end; p += 256)
        atomicAdd(&hist[edgeA[p].x >> 17], 1);
    __syncthreads();
    int a0 = hist[threadIdx.x * 2], a1 = hist[threadIdx.x * 2 + 1];
    ts[threadIdx.x] = a0 + a1;
    __syncthreads();
    for (int off = 1; off < 256; off <<= 1) {
        int t = (threadIdx.x >= off) ? ts[threadIdx.x - off] : 0;
        __syncthreads();
        ts[threadIdx.x] += t;
        __syncthreads();
    }
    int excl = threadIdx.x ? ts[threadIdx.x - 1] : 0;
    rstart[threadIdx.x * 2]     = excl;
    rstart[threadIdx.x * 2 + 1] = excl + a0;
    __syncthreads();
    const int node0 = b << BSHIFT;
    for (int i = threadIdx.x; i < BUCK_NODES; i += 256) {
        int n = node0 + i;
        if (n < N_NODES) row_ptr[n] = beg + rstart[i];
    }
    for (int p = beg + threadIdx.x; p < end; p += 256) {
        int2 e = edgeA[p];
        int ld = e.x >> 17;
        int r = atomicAdd(&lfill[ld], 1);
        edgeB[beg + rstart[ld] + r] = make_int2(e.x & 0x1FFFF, e.y);
    }
}

// ---------------------------------------------------------------------------
// support1 = bf16(x @ W1)    [N,128]@[128,64] -> [N,64]
// ---------------------------------------------------------------------------
__global__ __launch_bounds__(256) void k_gemm1(const float* __restrict__ x,
                                               const float* __restrict__ W1,
                                               unsigned short* __restrict__ s1) {
    __shared__ float xs[16][NFEAT];
    const int node0 = blockIdx.x * 16;
    const float4* x4 = (const float4*)(x + (size_t)node0 * NFEAT);
    float4* xs4 = (float4*)xs;
    for (int i = threadIdx.x; i < 16 * NFEAT / 4; i += 256) xs4[i] = x4[i];
    __syncthreads();

    const int j  = threadIdx.x & 63;
    const int l0 = (threadIdx.x >> 6) * 4;
    float acc0 = 0, acc1 = 0, acc2 = 0, acc3 = 0;
    for (int k = 0; k < NFEAT; k += 4) {
        float w0 = W1[(k + 0) * NHID + j];
        float w1 = W1[(k + 1) * NHID + j];
        float w2 = W1[(k + 2) * NHID + j];
        float w3 = W1[(k + 3) * NHID + j];
        float4 a0 = *(const float4*)&xs[l0 + 0][k];
        float4 a1 = *(const float4*)&xs[l0 + 1][k];
        float4 a2 = *(const float4*)&xs[l0 + 2][k];
        float4 a3 = *(const float4*)&xs[l0 + 3][k];
        acc0 += a0.x * w0 + a0.y * w1 + a0.z * w2 + a0.w * w3;
        acc1 += a1.x * w0 + a1.y * w1 + a1.z * w2 + a1.w * w3;
        acc2 += a2.x * w0 + a2.y * w1 + a2.z * w2 + a2.w * w3;
        acc3 += a3.x * w0 + a3.y * w1 + a3.z * w2 + a3.w * w3;
    }
    size_t base = (size_t)(node0 + l0) * NHID + j;
    s1[base]            = f2bf(acc0);
    s1[base + NHID]     = f2bf(acc1);
    s1[base + 2 * NHID] = f2bf(acc2);
    s1[base + 3 * NHID] = f2bf(acc3);
}

// ---------------------------------------------------------------------------
// Fused: h = relu(gather(s1) + b1);  s2 = bf16(h @ W2)
// One wave per node. Lane l: sub = l>>4 (edge slot), q = l&15 (feat quad).
// Each gather instruction covers 4 edges x 512 B; 8 edges/iter in main loop.
// ---------------------------------------------------------------------------
__global__ __launch_bounds__(256) void k_agg1g2(const int* __restrict__ row_ptr,
                                                const int2* __restrict__ edge2,
                                                const unsigned short* __restrict__ s1,
                                                const float* __restrict__ b1,
                                                const float* __restrict__ W2,
                                                unsigned short* __restrict__ s2) {
    __shared__ float hs[4][68];          // +4 pad: 16B-aligned rows, bank-offset 4
    __shared__ float w2s[NHID * NCLASS];
    for (int i = threadIdx.x; i < NHID * NCLASS; i += 256) w2s[i] = W2[i];

    const uint2* __restrict__ s1u2 = (const uint2*)s1;   // row = 16 uint2 (64 bf16)
    const int w   = threadIdx.x >> 6;
    const int n   = blockIdx.x * 4 + w;
    const int sub = (threadIdx.x >> 4) & 3;
    const int q   = threadIdx.x & 15;

    const int beg = row_ptr[n], end = row_ptr[n + 1];
    float ax = 0.f, ay = 0.f, az = 0.f, aw = 0.f;

    int p = beg;
    for (; p + 8 <= end; p += 8) {
        int2 e0 = edge2[p + sub];
        int2 e1 = edge2[p + sub + 4];
        uint2 u0 = s1u2[(size_t)e0.x * 16 + q];
        uint2 u1 = s1u2[(size_t)e1.x * 16 + q];
        float w0 = __int_as_float(e0.y);
        float w1 = __int_as_float(e1.y);
        ax += w0 * bflo(u0.x); ay += w0 * bfhi(u0.x);
        az += w0 * bflo(u0.y); aw += w0 * bfhi(u0.y);
        ax += w1 * bflo(u1.x); ay += w1 * bfhi(u1.x);
        az += w1 * bflo(u1.y); aw += w1 * bfhi(u1.y);
    }
    if (p < end) {   // masked epilogue: handles 1..7 remaining edges
        int i0 = p + sub, i1 = p + sub + 4;
        int j0 = min(i0, end - 1), j1 = min(i1, end - 1);
        int2 e0 = edge2[j0];
        int2 e1 = edge2[j1];
        uint2 u0 = s1u2[(size_t)e0.x * 16 + q];
        uint2 u1 = s1u2[(size_t)e1.x * 16 + q];
        float w0 = (i0 < end) ? __int_as_float(e0.y) : 0.f;
        float w1 = (i1 < end) ? __int_as_float(e1.y) : 0.f;
        ax += w0 * bflo(u0.x); ay += w0 * bfhi(u0.x);
        az += w0 * bflo(u0.y); aw += w0 * bfhi(u0.y);
        ax += w1 * bflo(u1.x); ay += w1 * bfhi(u1.x);
        az += w1 * bflo(u1.y); aw += w1 * bfhi(u1.y);
    }
    // combine the 4 sub-accumulators
    ax += __shfl_xor(ax, 16); ay += __shfl_xor(ay, 16);
    az += __shfl_xor(az, 16); aw += __shfl_xor(aw, 16);
    ax += __shfl_xor(ax, 32); ay += __shfl_xor(ay, 32);
    az += __shfl_xor(az, 32); aw += __shfl_xor(aw, 32);

    if (sub == 0 && threadIdx.x < 64 * 4) {   // lanes 0..15 of each wave
        float4 bb = ((const float4*)b1)[q];
        float4 v = make_float4(fmaxf(ax + bb.x, 0.f), fmaxf(ay + bb.y, 0.f),
                               fmaxf(az + bb.z, 0.f), fmaxf(aw + bb.w, 0.f));
        *(float4*)&hs[w][4 * q] = v;
    }
    __syncthreads();

    // gemm2 tail: 64 threads compute 4 nodes x 16 classes
    if (threadIdx.x < 64) {
        const int l = threadIdx.x >> 4;
        const int c = threadIdx.x & 15;
        float a = 0.f;
#pragma unroll
        for (int k = 0; k < NHID; ++k) a += hs[l][k] * w2s[k * NCLASS + c];
        s2[(size_t)(blockIdx.x * 4 + l) * NCLASS + c] = f2bf(a);
    }
}

// ---------------------------------------------------------------------------
// out = log_softmax(gather(s2) + b2)
// One wave per node. Lane l: sub = l>>4 (edge slot), c = l&15 (class).
// ---------------------------------------------------------------------------
__global__ __launch_bounds__(256) void k_agg2lsm(const int* __restrict__ row_ptr,
                                                 const int2* __restrict__ edge2,
                                                 const unsigned short* __restrict__ s2,
                                                 const float* __restrict__ b2,
                                                 float* __restrict__ out) {
    const int n   = blockIdx.x * 4 + (threadIdx.x >> 6);
    const int sub = (threadIdx.x >> 4) & 3;
    const int c   = threadIdx.x & 15;
    const int beg = row_ptr[n], end = row_ptr[n + 1];
    float acc = 0.f;

    int p = beg;
    for (; p + 8 <= end; p += 8) {
        int2 e0 = edge2[p + sub];
        int2 e1 = edge2[p + sub + 4];
        float v0 = bf2f(s2[(size_t)e0.x * NCLASS + c]);
        float v1 = bf2f(s2[(size_t)e1.x * NCLASS + c]);
        acc += __int_as_float(e0.y) * v0;
        acc += __int_as_float(e1.y) * v1;
    }
    if (p < end) {
        int i0 = p + sub, i1 = p + sub + 4;
        int j0 = min(i0, end - 1), j1 = min(i1, end - 1);
        int2 e0 = edge2[j0];
        int2 e1 = edge2[j1];
        float w0 = (i0 < end) ? __int_as_float(e0.y) : 0.f;
        float w1 = (i1 < end) ? __int_as_float(e1.y) : 0.f;
        acc += w0 * bf2f(s2[(size_t)e0.x * NCLASS + c]);
        acc += w1 * bf2f(s2[(size_t)e1.x * NCLASS + c]);
    }
    acc += __shfl_xor(acc, 16);
    acc += __shfl_xor(acc, 32);

    float v = acc + b2[c];
    float m = v;
#pragma unroll
    for (int off = 8; off >= 1; off >>= 1) m = fmaxf(m, __shfl_xor(m, off, 16));
    float s = __expf(v - m);
#pragma unroll
    for (int off = 8; off >= 1; off >>= 1) s += __shfl_xor(s, off, 16);
    if (sub == 0) out[(size_t)n * NCLASS + c] = v - m - __logf(s);
}

extern "C" void kernel_launch(void* const* d_in, const int* in_sizes, int n_in,
                              void* d_out, int out_size, void* d_ws, size_t ws_size,
                              hipStream_t stream) {
    const float* x   = (const float*)d_in[0];
    const int*   src = (const int*)d_in[1];
    const int*   dst = (const int*)d_in[2];
    const float* ew  = (const float*)d_in[3];
    const float* W1  = (const float*)d_in[4];
    const float* b1  = (const float*)d_in[5];
    const float* W2  = (const float*)d_in[6];
    const float* b2  = (const float*)d_in[7];
    float* out = (float*)d_out;

    // ws layout (~42.3 MB): s1 bf16[N*64] | s2 bf16[N*16] | edgeA int2[E] |
    // edgeB int2[E] | row_ptr[N+1] | bucket_cnt[196] | bucket_ptr[197] | fill[196]
    unsigned short* s1 = (unsigned short*)d_ws;
    unsigned short* s2 = s1 + (size_t)N_NODES * NHID;
    int2* edgeA        = (int2*)(s2 + (size_t)N_NODES * NCLASS);
    int2* edgeB        = edgeA + N_EDGES;
    int*  row_ptr      = (int*)(edgeB + N_EDGES);
    int*  bucket_cnt   = row_ptr + (N_NODES + 1);
    int*  bucket_ptr   = bucket_cnt + NBUCK;
    int*  fill         = bucket_ptr + (NBUCK + 1);

    hipMemsetAsync(bucket_cnt, 0, sizeof(int) * NBUCK, stream);

    k_bhist   <<<NB_SCAT, 256, 0, stream>>>(dst, bucket_cnt);
    k_bscan   <<<1, 256, 0, stream>>>(bucket_cnt, bucket_ptr, fill, row_ptr);
    k_bscatter<<<NB_SCAT, 256, 0, stream>>>(dst, src, ew, fill, edgeA);
    k_bsort   <<<NBUCK, 256, 0, stream>>>(bucket_ptr, edgeA, edgeB, row_ptr);

    k_gemm1  <<<N_NODES / 16, 256, 0, stream>>>(x, W1, s1);
    k_agg1g2 <<<N_NODES / 4, 256, 0, stream>>>(row_ptr, edgeB, s1, b1, W2, s2);
    k_agg2lsm<<<N_NODES / 4, 256, 0, stream>>>(row_ptr, edgeB, s2, b2, out);
}

// Round 8
// 293.752 us; speedup vs baseline: 2.2418x; 1.0946x over previous
//
#include <hip/hip_runtime.h>

#define N_NODES 100000
#define N_EDGES 1600000
#define NFEAT 128
#define NHID 64
#define NCLASS 16

#define BSHIFT 9                                   // 512 nodes per bucket
#define BUCK_NODES 512
#define NBUCK ((N_NODES + BUCK_NODES - 1) >> BSHIFT)   // 196
#define EDGE_TILE 8192
#define NB_SCAT ((N_EDGES + EDGE_TILE - 1) / EDGE_TILE) // 196
#define NB_GEMM1 (N_NODES / 16)                         // 6250

__device__ __forceinline__ float bf2f(unsigned short u) {
    return __uint_as_float(((unsigned int)u) << 16);
}
__device__ __forceinline__ float bflo(unsigned int u) {
    return __uint_as_float(u << 16);
}
__device__ __forceinline__ float bfhi(unsigned int u) {
    return __uint_as_float(u & 0xFFFF0000u);
}
__device__ __forceinline__ unsigned short f2bf(float f) {
    unsigned int b = __float_as_uint(f);
    b += 0x7FFFu + ((b >> 16) & 1u);   // RNE
    return (unsigned short)(b >> 16);
}
// packed edge: src in bits [0,17), weight fixed-point 15b in [17,32)
__device__ __forceinline__ float wdec(unsigned int u) {
    return (float)(u >> 17) * (1.0f / 32767.0f);
}

// ---------------------------------------------------------------------------
// Fused: gemm1 (blocks 0..6249) + bucket histogram (blocks 6250..6445)
// ---------------------------------------------------------------------------
__global__ __launch_bounds__(256) void k_gemm1_hist(const float* __restrict__ x,
                                                    const float* __restrict__ W1,
                                                    unsigned short* __restrict__ s1,
                                                    const int* __restrict__ dst,
                                                    int* __restrict__ bucket_cnt) {
    __shared__ float xs[16][NFEAT];
    __shared__ int hist[NBUCK];
    if (blockIdx.x >= NB_GEMM1) {
        // --- histogram part ---
        const int bid = blockIdx.x - NB_GEMM1;
        for (int i = threadIdx.x; i < NBUCK; i += 256) hist[i] = 0;
        __syncthreads();
        const int base = bid * EDGE_TILE;
        for (int i = threadIdx.x; i < EDGE_TILE; i += 256) {
            int e = base + i;
            if (e < N_EDGES) atomicAdd(&hist[dst[e] >> BSHIFT], 1);
        }
        __syncthreads();
        for (int i = threadIdx.x; i < NBUCK; i += 256)
            if (hist[i]) atomicAdd(&bucket_cnt[i], hist[i]);
        return;
    }
    // --- gemm1 part ---
    const int node0 = blockIdx.x * 16;
    const float4* x4 = (const float4*)(x + (size_t)node0 * NFEAT);
    float4* xs4 = (float4*)xs;
    for (int i = threadIdx.x; i < 16 * NFEAT / 4; i += 256) xs4[i] = x4[i];
    __syncthreads();

    const int j  = threadIdx.x & 63;
    const int l0 = (threadIdx.x >> 6) * 4;
    float acc0 = 0, acc1 = 0, acc2 = 0, acc3 = 0;
    for (int k = 0; k < NFEAT; k += 4) {
        float w0 = W1[(k + 0) * NHID + j];
        float w1 = W1[(k + 1) * NHID + j];
        float w2 = W1[(k + 2) * NHID + j];
        float w3 = W1[(k + 3) * NHID + j];
        float4 a0 = *(const float4*)&xs[l0 + 0][k];
        float4 a1 = *(const float4*)&xs[l0 + 1][k];
        float4 a2 = *(const float4*)&xs[l0 + 2][k];
        float4 a3 = *(const float4*)&xs[l0 + 3][k];
        acc0 += a0.x * w0 + a0.y * w1 + a0.z * w2 + a0.w * w3;
        acc1 += a1.x * w0 + a1.y * w1 + a1.z * w2 + a1.w * w3;
        acc2 += a2.x * w0 + a2.y * w1 + a2.z * w2 + a2.w * w3;
        acc3 += a3.x * w0 + a3.y * w1 + a3.z * w2 + a3.w * w3;
    }
    size_t base = (size_t)(node0 + l0) * NHID + j;
    s1[base]            = f2bf(acc0);
    s1[base + NHID]     = f2bf(acc1);
    s1[base + 2 * NHID] = f2bf(acc2);
    s1[base + 3 * NHID] = f2bf(acc3);
}

// ---------------------------------------------------------------------------
// Exclusive scan of 196 bucket counts (single block)
// ---------------------------------------------------------------------------
__global__ __launch_bounds__(256) void k_bscan(const int* __restrict__ bucket_cnt,
                                               int* __restrict__ bucket_ptr,
                                               int* __restrict__ fill,
                                               int* __restrict__ row_ptr) {
    __shared__ int ts[256];
    int v = (threadIdx.x < NBUCK) ? bucket_cnt[threadIdx.x] : 0;
    ts[threadIdx.x] = v;
    __syncthreads();
    for (int off = 1; off < 256; off <<= 1) {
        int t = (threadIdx.x >= off) ? ts[threadIdx.x - off] : 0;
        __syncthreads();
        ts[threadIdx.x] += t;
        __syncthreads();
    }
    int excl = threadIdx.x ? ts[threadIdx.x - 1] : 0;
    if (threadIdx.x < NBUCK) { bucket_ptr[threadIdx.x] = excl; fill[threadIdx.x] = excl; }
    if (threadIdx.x == 0) { bucket_ptr[NBUCK] = N_EDGES; row_ptr[N_NODES] = N_EDGES; }
}

// ---------------------------------------------------------------------------
// Bucket-scatter into ~336 B contiguous runs.
// edgeA record: (src 17b | local_dst 9b, fp32 weight)
// ---------------------------------------------------------------------------
__global__ __launch_bounds__(256) void k_bscatter(const int* __restrict__ dst,
                                                  const int* __restrict__ src,
                                                  const float* __restrict__ ew,
                                                  int* __restrict__ fill,
                                                  int2* __restrict__ edgeA) {
    __shared__ int hist[NBUCK], bbase[NBUCK], bfill[NBUCK];
    for (int i = threadIdx.x; i < NBUCK; i += 256) { hist[i] = 0; bfill[i] = 0; }
    __syncthreads();
    const int base = blockIdx.x * EDGE_TILE;
    for (int i = threadIdx.x; i < EDGE_TILE; i += 256) {
        int e = base + i;
        if (e < N_EDGES) atomicAdd(&hist[dst[e] >> BSHIFT], 1);
    }
    __syncthreads();
    for (int i = threadIdx.x; i < NBUCK; i += 256)
        bbase[i] = hist[i] ? atomicAdd(&fill[i], hist[i]) : 0;
    __syncthreads();
    for (int i = threadIdx.x; i < EDGE_TILE; i += 256) {
        int e = base + i;
        if (e >= N_EDGES) break;
        int d = dst[e];
        int b = d >> BSHIFT;
        int r = atomicAdd(&bfill[b], 1);
        edgeA[bbase[b] + r] = make_int2(src[e] | ((d & (BUCK_NODES - 1)) << 17),
                                        __float_as_int(ew[e]));
    }
}

// ---------------------------------------------------------------------------
// In-bucket exact sort by dst; emits row_ptr and packed 4 B edge records
// edgeB: src(17b) | w15(15b)
// ---------------------------------------------------------------------------
__global__ __launch_bounds__(256) void k_bsort(const int* __restrict__ bucket_ptr,
                                               const int2* __restrict__ edgeA,
                                               unsigned int* __restrict__ edgeB,
                                               int* __restrict__ row_ptr) {
    __shared__ int hist[BUCK_NODES], rstart[BUCK_NODES], lfill[BUCK_NODES];
    __shared__ int ts[256];
    const int b = blockIdx.x;
    const int beg = bucket_ptr[b], end = bucket_ptr[b + 1];
    for (int i = threadIdx.x; i < BUCK_NODES; i += 256) { hist[i] = 0; lfill[i] = 0; }
    __syncthreads();
    for (int p = beg + threadIdx.x; p < end; p += 256)
        atomicAdd(&hist[edgeA[p].x >> 17], 1);
    __syncthreads();
    int a0 = hist[threadIdx.x * 2], a1 = hist[threadIdx.x * 2 + 1];
    ts[threadIdx.x] = a0 + a1;
    __syncthreads();
    for (int off = 1; off < 256; off <<= 1) {
        int t = (threadIdx.x >= off) ? ts[threadIdx.x - off] : 0;
        __syncthreads();
        ts[threadIdx.x] += t;
        __syncthreads();
    }
    int excl = threadIdx.x ? ts[threadIdx.x - 1] : 0;
    rstart[threadIdx.x * 2]     = excl;
    rstart[threadIdx.x * 2 + 1] = excl + a0;
    __syncthreads();
    const int node0 = b << BSHIFT;
    for (int i = threadIdx.x; i < BUCK_NODES; i += 256) {
        int n = node0 + i;
        if (n < N_NODES) row_ptr[n] = beg + rstart[i];
    }
    for (int p = beg + threadIdx.x; p < end; p += 256) {
        int2 e = edgeA[p];
        int ld = e.x >> 17;
        int r = atomicAdd(&lfill[ld], 1);
        unsigned int w15 = (unsigned int)(__int_as_float(e.y) * 32767.0f + 0.5f);
        edgeB[beg + rstart[ld] + r] = (unsigned int)(e.x & 0x1FFFF) | (w15 << 17);
    }
}

// ---------------------------------------------------------------------------
// Fused: h = relu(gather(s1) + b1);  s2 = bf16(h @ W2)
// One wave per node. Lane l: sub = l>>3 (edge slot 0..7), r = l&7 (feat octet).
// One uint4 gather instruction covers 8 edge-rows = 1 KB. 16 edges/iter.
// ---------------------------------------------------------------------------
__global__ __launch_bounds__(256) void k_agg1g2(const int* __restrict__ row_ptr,
                                                const unsigned int* __restrict__ edge2,
                                                const unsigned short* __restrict__ s1,
                                                const float* __restrict__ b1,
                                                const float* __restrict__ W2,
                                                unsigned short* __restrict__ s2) {
    __shared__ float hs[4][68];
    __shared__ float w2s[NHID * NCLASS];
    for (int i = threadIdx.x; i < NHID * NCLASS; i += 256) w2s[i] = W2[i];

    const uint4* __restrict__ s1u4 = (const uint4*)s1;   // row = 8 uint4 (64 bf16)
    const int w   = threadIdx.x >> 6;
    const int n   = blockIdx.x * 4 + w;
    const int sub = (threadIdx.x >> 3) & 7;
    const int r   = threadIdx.x & 7;

    const int beg = row_ptr[n], end = row_ptr[n + 1];
    float a0 = 0, a1 = 0, a2 = 0, a3 = 0, a4 = 0, a5 = 0, a6 = 0, a7 = 0;

    int p = beg;
    for (; p + 16 <= end; p += 16) {
        unsigned int e0 = edge2[p + sub];
        unsigned int e1 = edge2[p + sub + 8];
        uint4 u0 = s1u4[(size_t)(e0 & 0x1FFFF) * 8 + r];
        uint4 u1 = s1u4[(size_t)(e1 & 0x1FFFF) * 8 + r];
        float w0 = wdec(e0), w1 = wdec(e1);
        a0 += w0 * bflo(u0.x); a1 += w0 * bfhi(u0.x);
        a2 += w0 * bflo(u0.y); a3 += w0 * bfhi(u0.y);
        a4 += w0 * bflo(u0.z); a5 += w0 * bfhi(u0.z);
        a6 += w0 * bflo(u0.w); a7 += w0 * bfhi(u0.w);
        a0 += w1 * bflo(u1.x); a1 += w1 * bfhi(u1.x);
        a2 += w1 * bflo(u1.y); a3 += w1 * bfhi(u1.y);
        a4 += w1 * bflo(u1.z); a5 += w1 * bfhi(u1.z);
        a6 += w1 * bflo(u1.w); a7 += w1 * bfhi(u1.w);
    }
    if (p < end) {   // masked epilogue: 1..15 remaining edges
        int i0 = p + sub, i1 = p + sub + 8;
        int j0 = min(i0, end - 1), j1 = min(i1, end - 1);
        unsigned int e0 = edge2[j0];
        unsigned int e1 = edge2[j1];
        uint4 u0 = s1u4[(size_t)(e0 & 0x1FFFF) * 8 + r];
        uint4 u1 = s1u4[(size_t)(e1 & 0x1FFFF) * 8 + r];
        float w0 = (i0 < end) ? wdec(e0) : 0.f;
        float w1 = (i1 < end) ? wdec(e1) : 0.f;
        a0 += w0 * bflo(u0.x); a1 += w0 * bfhi(u0.x);
        a2 += w0 * bflo(u0.y); a3 += w0 * bfhi(u0.y);
        a4 += w0 * bflo(u0.z); a5 += w0 * bfhi(u0.z);
        a6 += w0 * bflo(u0.w); a7 += w0 * bfhi(u0.w);
        a0 += w1 * bflo(u1.x); a1 += w1 * bfhi(u1.x);
        a2 += w1 * bflo(u1.y); a3 += w1 * bfhi(u1.y);
        a4 += w1 * bflo(u1.z); a5 += w1 * bfhi(u1.z);
        a6 += w1 * bflo(u1.w); a7 += w1 * bfhi(u1.w);
    }
    // combine across the 8 edge-slots (lane bits 3,4,5)
#pragma unroll
    for (int off = 8; off <= 32; off <<= 1) {
        a0 += __shfl_xor(a0, off); a1 += __shfl_xor(a1, off);
        a2 += __shfl_xor(a2, off); a3 += __shfl_xor(a3, off);
        a4 += __shfl_xor(a4, off); a5 += __shfl_xor(a5, off);
        a6 += __shfl_xor(a6, off); a7 += __shfl_xor(a7, off);
    }
    if (sub == 0) {   // lanes 0..7 of each wave hold feats [8r, 8r+8)
        float4 bA = ((const float4*)b1)[2 * r];
        float4 bB = ((const float4*)b1)[2 * r + 1];
        float4 vA = make_float4(fmaxf(a0 + bA.x, 0.f), fmaxf(a1 + bA.y, 0.f),
                                fmaxf(a2 + bA.z, 0.f), fmaxf(a3 + bA.w, 0.f));
        float4 vB = make_float4(fmaxf(a4 + bB.x, 0.f), fmaxf(a5 + bB.y, 0.f),
                                fmaxf(a6 + bB.z, 0.f), fmaxf(a7 + bB.w, 0.f));
        *(float4*)&hs[w][8 * r]     = vA;
        *(float4*)&hs[w][8 * r + 4] = vB;
    }
    __syncthreads();

    // gemm2 tail: 64 threads compute 4 nodes x 16 classes
    if (threadIdx.x < 64) {
        const int l = threadIdx.x >> 4;
        const int c = threadIdx.x & 15;
        float a = 0.f;
#pragma unroll
        for (int k = 0; k < NHID; ++k) a += hs[l][k] * w2s[k * NCLASS + c];
        s2[(size_t)(blockIdx.x * 4 + l) * NCLASS + c] = f2bf(a);
    }
}

// ---------------------------------------------------------------------------
// out = log_softmax(gather(s2) + b2)
// R4 layout (4 indep nodes/wave, 16 lanes/node) + 8-edge unroll -> 32 loads
// in flight per wave.
// ---------------------------------------------------------------------------
__global__ __launch_bounds__(256) void k_agg2lsm(const int* __restrict__ row_ptr,
                                                 const unsigned int* __restrict__ edge2,
                                                 const unsigned short* __restrict__ s2,
                                                 const float* __restrict__ b2,
                                                 float* __restrict__ out) {
    const int n = blockIdx.x * 16 + (threadIdx.x >> 4);
    const int c = threadIdx.x & 15;
    const int beg = row_ptr[n], end = row_ptr[n + 1];
    float acc = 0.f;
    int p = beg;
    for (; p + 8 <= end; p += 8) {
        unsigned int e0 = edge2[p],     e1 = edge2[p + 1];
        unsigned int e2 = edge2[p + 2], e3 = edge2[p + 3];
        unsigned int e4 = edge2[p + 4], e5 = edge2[p + 5];
        unsigned int e6 = edge2[p + 6], e7 = edge2[p + 7];
        acc += wdec(e0) * bf2f(s2[(size_t)(e0 & 0x1FFFF) * NCLASS + c]);
        acc += wdec(e1) * bf2f(s2[(size_t)(e1 & 0x1FFFF) * NCLASS + c]);
        acc += wdec(e2) * bf2f(s2[(size_t)(e2 & 0x1FFFF) * NCLASS + c]);
        acc += wdec(e3) * bf2f(s2[(size_t)(e3 & 0x1FFFF) * NCLASS + c]);
        acc += wdec(e4) * bf2f(s2[(size_t)(e4 & 0x1FFFF) * NCLASS + c]);
        acc += wdec(e5) * bf2f(s2[(size_t)(e5 & 0x1FFFF) * NCLASS + c]);
        acc += wdec(e6) * bf2f(s2[(size_t)(e6 & 0x1FFFF) * NCLASS + c]);
        acc += wdec(e7) * bf2f(s2[(size_t)(e7 & 0x1FFFF) * NCLASS + c]);
    }
    if (p < end) {   // masked epilogue, 1..7 edges
#pragma unroll
        for (int k = 0; k < 7; ++k) {
            int idx = p + k;
            unsigned int e = edge2[min(idx, end - 1)];
            float wv = (idx < end) ? wdec(e) : 0.f;
            acc += wv * bf2f(s2[(size_t)(e & 0x1FFFF) * NCLASS + c]);
        }
    }
    float v = acc + b2[c];
    float m = v;
#pragma unroll
    for (int off = 8; off >= 1; off >>= 1) m = fmaxf(m, __shfl_xor(m, off, 16));
    float s = __expf(v - m);
#pragma unroll
    for (int off = 8; off >= 1; off >>= 1) s += __shfl_xor(s, off, 16);
    out[(size_t)n * NCLASS + c] = v - m - __logf(s);
}

extern "C" void kernel_launch(void* const* d_in, const int* in_sizes, int n_in,
                              void* d_out, int out_size, void* d_ws, size_t ws_size,
                              hipStream_t stream) {
    const float* x   = (const float*)d_in[0];
    const int*   src = (const int*)d_in[1];
    const int*   dst = (const int*)d_in[2];
    const float* ew  = (const float*)d_in[3];
    const float* W1  = (const float*)d_in[4];
    const float* b1  = (const float*)d_in[5];
    const float* W2  = (const float*)d_in[6];
    const float* b2  = (const float*)d_in[7];
    float* out = (float*)d_out;

    // ws layout (~36 MB): s1 bf16[N*64] | s2 bf16[N*16] | edgeA int2[E] |
    // edgeB uint[E] | row_ptr[N+1] | bucket_cnt[196] | bucket_ptr[197] | fill[196]
    unsigned short* s1 = (unsigned short*)d_ws;
    unsigned short* s2 = s1 + (size_t)N_NODES * NHID;
    int2* edgeA        = (int2*)(s2 + (size_t)N_NODES * NCLASS);
    unsigned int* edgeB = (unsigned int*)(edgeA + N_EDGES);
    int*  row_ptr      = (int*)(edgeB + N_EDGES);
    int*  bucket_cnt   = row_ptr + (N_NODES + 1);
    int*  bucket_ptr   = bucket_cnt + NBUCK;
    int*  fill         = bucket_ptr + (NBUCK + 1);

    hipMemsetAsync(bucket_cnt, 0, sizeof(int) * NBUCK, stream);

    k_gemm1_hist<<<NB_GEMM1 + NB_SCAT, 256, 0, stream>>>(x, W1, s1, dst, bucket_cnt);
    k_bscan     <<<1, 256, 0, stream>>>(bucket_cnt, bucket_ptr, fill, row_ptr);
    k_bscatter  <<<NB_SCAT, 256, 0, stream>>>(dst, src, ew, fill, edgeA);
    k_bsort     <<<NBUCK, 256, 0, stream>>>(bucket_ptr, edgeA, edgeB, row_ptr);

    k_agg1g2 <<<N_NODES / 4, 256, 0, stream>>>(row_ptr, edgeB, s1, b1, W2, s2);
    k_agg2lsm<<<N_NODES / 16, 256, 0, stream>>>(row_ptr, edgeB, s2, b2, out);
}

// Round 9
// 267.912 us; speedup vs baseline: 2.4581x; 1.0964x over previous
//
#include <hip/hip_runtime.h>

#define N_NODES 100000
#define N_EDGES 1600000
#define NFEAT 128
#define NHID 64
#define NCLASS 16

#define BSHIFT 9                                   // 512 nodes per bucket
#define BUCK_NODES 512
#define NBUCK ((N_NODES + BUCK_NODES - 1) >> BSHIFT)   // 196
#define EDGE_TILE 8192
#define NB_SCAT ((N_EDGES + EDGE_TILE - 1) / EDGE_TILE) // 196
#define N_TILES (N_NODES / 64 + 1)                      // 1563 tiles of 64 nodes
#define NB_GEMM1 782                                    // grid-stride: 2 tiles/block

typedef __attribute__((ext_vector_type(8))) short short8;
typedef __attribute__((ext_vector_type(4))) float float4v;

__device__ __forceinline__ float bf2f(unsigned short u) {
    return __uint_as_float(((unsigned int)u) << 16);
}
__device__ __forceinline__ float bflo(unsigned int u) {
    return __uint_as_float(u << 16);
}
__device__ __forceinline__ float bfhi(unsigned int u) {
    return __uint_as_float(u & 0xFFFF0000u);
}
__device__ __forceinline__ unsigned short f2bf(float f) {
    unsigned int b = __float_as_uint(f);
    b += 0x7FFFu + ((b >> 16) & 1u);   // RNE
    return (unsigned short)(b >> 16);
}
// packed edge: src in bits [0,17), weight fixed-point 15b in [17,32)
__device__ __forceinline__ float wdec(unsigned int u) {
    return (float)(u >> 17) * (1.0f / 32767.0f);
}

// ---------------------------------------------------------------------------
// Fused: MFMA gemm1 (blocks 0..781, grid-stride over 64-node tiles)
//        + bucket histogram (blocks 782..977)
// s1 = bf16(x @ W1). Wave = 16 nodes x 64 hid = 16 MFMAs (16x16x32 bf16).
// W1^T staged once per block into LDS (bf16, stride 136 -> 16B-aligned frags);
// all 16 B-fragments live in VGPRs across tiles.
// ---------------------------------------------------------------------------
__global__ __launch_bounds__(256) void k_gemm1_hist(const float* __restrict__ x,
                                                    const float* __restrict__ W1,
                                                    unsigned short* __restrict__ s1,
                                                    const int* __restrict__ dst,
                                                    int* __restrict__ bucket_cnt) {
    __shared__ unsigned short w1t[64][136];   // [n][k], padded for alignment
    __shared__ int hist[NBUCK];
    if (blockIdx.x >= NB_GEMM1) {
        // --- histogram part ---
        const int bid = blockIdx.x - NB_GEMM1;
        for (int i = threadIdx.x; i < NBUCK; i += 256) hist[i] = 0;
        __syncthreads();
        const int base = bid * EDGE_TILE;
        for (int i = threadIdx.x; i < EDGE_TILE; i += 256) {
            int e = base + i;
            if (e < N_EDGES) atomicAdd(&hist[dst[e] >> BSHIFT], 1);
        }
        __syncthreads();
        for (int i = threadIdx.x; i < NBUCK; i += 256)
            if (hist[i]) atomicAdd(&bucket_cnt[i], hist[i]);
        return;
    }
    // --- gemm1 part ---
    // stage W1^T as bf16 (coalesced global read; strided LDS write, once/block)
    for (int i = threadIdx.x; i < NFEAT * NHID; i += 256) {
        int n = i & 63, k = i >> 6;
        w1t[n][k] = f2bf(W1[k * NHID + n]);
    }
    __syncthreads();

    const int lane = threadIdx.x & 63;
    const int wv   = threadIdx.x >> 6;
    const int m    = lane & 15;        // node-row / B-col within tile
    const int quad = lane >> 4;        // k-octet selector

    // B fragments: bfrag[kt][nt] lane holds W1[kt*32+quad*8 .. +8][nt*16+m]
    short8 bfrag[4][4];
#pragma unroll
    for (int kt = 0; kt < 4; ++kt)
#pragma unroll
        for (int nt = 0; nt < 4; ++nt)
            bfrag[kt][nt] = *(const short8*)&w1t[nt * 16 + m][kt * 32 + quad * 8];

    for (int tile = blockIdx.x; tile < N_TILES; tile += NB_GEMM1) {
        const int node0 = tile * 64 + wv * 16;
        if (node0 >= N_NODES) continue;    // exact: N_NODES % 16 == 0
        const float4* xr = (const float4*)(x + (size_t)node0 * NFEAT);
        float4v acc[4] = {{0.f,0.f,0.f,0.f},{0.f,0.f,0.f,0.f},
                          {0.f,0.f,0.f,0.f},{0.f,0.f,0.f,0.f}};
#pragma unroll
        for (int kt = 0; kt < 4; ++kt) {
            // lane loads x[node0+m][kt*32+quad*8 .. +8] (two coalesced float4)
            float4 f0 = xr[m * 32 + kt * 8 + quad * 2];
            float4 f1 = xr[m * 32 + kt * 8 + quad * 2 + 1];
            short8 a;
            a[0] = (short)f2bf(f0.x); a[1] = (short)f2bf(f0.y);
            a[2] = (short)f2bf(f0.z); a[3] = (short)f2bf(f0.w);
            a[4] = (short)f2bf(f1.x); a[5] = (short)f2bf(f1.y);
            a[6] = (short)f2bf(f1.z); a[7] = (short)f2bf(f1.w);
#pragma unroll
            for (int nt = 0; nt < 4; ++nt)
                acc[nt] = __builtin_amdgcn_mfma_f32_16x16x32_bf16(
                    a, bfrag[kt][nt], acc[nt], 0, 0, 0);
        }
        // C/D layout: col = lane&15 (=m), row = quad*4 + reg
#pragma unroll
        for (int nt = 0; nt < 4; ++nt)
#pragma unroll
            for (int i = 0; i < 4; ++i)
                s1[(size_t)(node0 + quad * 4 + i) * NHID + nt * 16 + m] =
                    f2bf(acc[nt][i]);
    }
}

// ---------------------------------------------------------------------------
// Exclusive scan of 196 bucket counts (single block)
// ---------------------------------------------------------------------------
__global__ __launch_bounds__(256) void k_bscan(const int* __restrict__ bucket_cnt,
                                               int* __restrict__ bucket_ptr,
                                               int* __restrict__ fill,
                                               int* __restrict__ row_ptr) {
    __shared__ int ts[256];
    int v = (threadIdx.x < NBUCK) ? bucket_cnt[threadIdx.x] : 0;
    ts[threadIdx.x] = v;
    __syncthreads();
    for (int off = 1; off < 256; off <<= 1) {
        int t = (threadIdx.x >= off) ? ts[threadIdx.x - off] : 0;
        __syncthreads();
        ts[threadIdx.x] += t;
        __syncthreads();
    }
    int excl = threadIdx.x ? ts[threadIdx.x - 1] : 0;
    if (threadIdx.x < NBUCK) { bucket_ptr[threadIdx.x] = excl; fill[threadIdx.x] = excl; }
    if (threadIdx.x == 0) { bucket_ptr[NBUCK] = N_EDGES; row_ptr[N_NODES] = N_EDGES; }
}

// ---------------------------------------------------------------------------
// Bucket-scatter into ~336 B contiguous runs.
// edgeA record: (src 17b | local_dst 9b, fp32 weight)
// ---------------------------------------------------------------------------
__global__ __launch_bounds__(256) void k_bscatter(const int* __restrict__ dst,
                                                  const int* __restrict__ src,
                                                  const float* __restrict__ ew,
                                                  int* __restrict__ fill,
                                                  int2* __restrict__ edgeA) {
    __shared__ int hist[NBUCK], bbase[NBUCK], bfill[NBUCK];
    for (int i = threadIdx.x; i < NBUCK; i += 256) { hist[i] = 0; bfill[i] = 0; }
    __syncthreads();
    const int base = blockIdx.x * EDGE_TILE;
    for (int i = threadIdx.x; i < EDGE_TILE; i += 256) {
        int e = base + i;
        if (e < N_EDGES) atomicAdd(&hist[dst[e] >> BSHIFT], 1);
    }
    __syncthreads();
    for (int i = threadIdx.x; i < NBUCK; i += 256)
        bbase[i] = hist[i] ? atomicAdd(&fill[i], hist[i]) : 0;
    __syncthreads();
    for (int i = threadIdx.x; i < EDGE_TILE; i += 256) {
        int e = base + i;
        if (e >= N_EDGES) break;
        int d = dst[e];
        int b = d >> BSHIFT;
        int r = atomicAdd(&bfill[b], 1);
        edgeA[bbase[b] + r] = make_int2(src[e] | ((d & (BUCK_NODES - 1)) << 17),
                                        __float_as_int(ew[e]));
    }
}

// ---------------------------------------------------------------------------
// In-bucket exact sort by dst; emits row_ptr and packed 4 B edge records
// edgeB: src(17b) | w15(15b)
// ---------------------------------------------------------------------------
__global__ __launch_bounds__(256) void k_bsort(const int* __restrict__ bucket_ptr,
                                               const int2* __restrict__ edgeA,
                                               unsigned int* __restrict__ edgeB,
                                               int* __restrict__ row_ptr) {
    __shared__ int hist[BUCK_NODES], rstart[BUCK_NODES], lfill[BUCK_NODES];
    __shared__ int ts[256];
    const int b = blockIdx.x;
    const int beg = bucket_ptr[b], end = bucket_ptr[b + 1];
    for (int i = threadIdx.x; i < BUCK_NODES; i += 256) { hist[i] = 0; lfill[i] = 0; }
    __syncthreads();
    for (int p = beg + threadIdx.x; p < end; p += 256)
        atomicAdd(&hist[edgeA[p].x >> 17], 1);
    __syncthreads();
    int a0 = hist[threadIdx.x * 2], a1 = hist[threadIdx.x * 2 + 1];
    ts[threadIdx.x] = a0 + a1;
    __syncthreads();
    for (int off = 1; off < 256; off <<= 1) {
        int t = (threadIdx.x >= off) ? ts[threadIdx.x - off] : 0;
        __syncthreads();
        ts[threadIdx.x] += t;
        __syncthreads();
    }
    int excl = threadIdx.x ? ts[threadIdx.x - 1] : 0;
    rstart[threadIdx.x * 2]     = excl;
    rstart[threadIdx.x * 2 + 1] = excl + a0;
    __syncthreads();
    const int node0 = b << BSHIFT;
    for (int i = threadIdx.x; i < BUCK_NODES; i += 256) {
        int n = node0 + i;
        if (n < N_NODES) row_ptr[n] = beg + rstart[i];
    }
    for (int p = beg + threadIdx.x; p < end; p += 256) {
        int2 e = edgeA[p];
        int ld = e.x >> 17;
        int r = atomicAdd(&lfill[ld], 1);
        unsigned int w15 = (unsigned int)(__int_as_float(e.y) * 32767.0f + 0.5f);
        edgeB[beg + rstart[ld] + r] = (unsigned int)(e.x & 0x1FFFF) | (w15 << 17);
    }
}

// ---------------------------------------------------------------------------
// Fused: h = relu(gather(s1) + b1);  s2 = bf16(h @ W2)
// One wave per node. Lane l: sub = l>>3 (edge slot 0..7), r = l&7 (feat octet).
// One uint4 gather instruction covers 8 edge-rows = 1 KB. 16 edges/iter.
// ---------------------------------------------------------------------------
__global__ __launch_bounds__(256) void k_agg1g2(const int* __restrict__ row_ptr,
                                                const unsigned int* __restrict__ edge2,
                                                const unsigned short* __restrict__ s1,
                                                const float* __restrict__ b1,
                                                const float* __restrict__ W2,
                                                unsigned short* __restrict__ s2) {
    __shared__ float hs[4][68];
    __shared__ float w2s[NHID * NCLASS];
    for (int i = threadIdx.x; i < NHID * NCLASS; i += 256) w2s[i] = W2[i];

    const uint4* __restrict__ s1u4 = (const uint4*)s1;   // row = 8 uint4 (64 bf16)
    const int w   = threadIdx.x >> 6;
    const int n   = blockIdx.x * 4 + w;
    const int sub = (threadIdx.x >> 3) & 7;
    const int r   = threadIdx.x & 7;

    const int beg = row_ptr[n], end = row_ptr[n + 1];
    float a0 = 0, a1 = 0, a2 = 0, a3 = 0, a4 = 0, a5 = 0, a6 = 0, a7 = 0;

    int p = beg;
    for (; p + 16 <= end; p += 16) {
        unsigned int e0 = edge2[p + sub];
        unsigned int e1 = edge2[p + sub + 8];
        uint4 u0 = s1u4[(size_t)(e0 & 0x1FFFF) * 8 + r];
        uint4 u1 = s1u4[(size_t)(e1 & 0x1FFFF) * 8 + r];
        float w0 = wdec(e0), w1 = wdec(e1);
        a0 += w0 * bflo(u0.x); a1 += w0 * bfhi(u0.x);
        a2 += w0 * bflo(u0.y); a3 += w0 * bfhi(u0.y);
        a4 += w0 * bflo(u0.z); a5 += w0 * bfhi(u0.z);
        a6 += w0 * bflo(u0.w); a7 += w0 * bfhi(u0.w);
        a0 += w1 * bflo(u1.x); a1 += w1 * bfhi(u1.x);
        a2 += w1 * bflo(u1.y); a3 += w1 * bfhi(u1.y);
        a4 += w1 * bflo(u1.z); a5 += w1 * bfhi(u1.z);
        a6 += w1 * bflo(u1.w); a7 += w1 * bfhi(u1.w);
    }
    if (p < end) {   // masked epilogue: 1..15 remaining edges
        int i0 = p + sub, i1 = p + sub + 8;
        int j0 = min(i0, end - 1), j1 = min(i1, end - 1);
        unsigned int e0 = edge2[j0];
        unsigned int e1 = edge2[j1];
        uint4 u0 = s1u4[(size_t)(e0 & 0x1FFFF) * 8 + r];
        uint4 u1 = s1u4[(size_t)(e1 & 0x1FFFF) * 8 + r];
        float w0 = (i0 < end) ? wdec(e0) : 0.f;
        float w1 = (i1 < end) ? wdec(e1) : 0.f;
        a0 += w0 * bflo(u0.x); a1 += w0 * bfhi(u0.x);
        a2 += w0 * bflo(u0.y); a3 += w0 * bfhi(u0.y);
        a4 += w0 * bflo(u0.z); a5 += w0 * bfhi(u0.z);
        a6 += w0 * bflo(u0.w); a7 += w0 * bfhi(u0.w);
        a0 += w1 * bflo(u1.x); a1 += w1 * bfhi(u1.x);
        a2 += w1 * bflo(u1.y); a3 += w1 * bfhi(u1.y);
        a4 += w1 * bflo(u1.z); a5 += w1 * bfhi(u1.z);
        a6 += w1 * bflo(u1.w); a7 += w1 * bfhi(u1.w);
    }
    // combine across the 8 edge-slots (lane bits 3,4,5)
#pragma unroll
    for (int off = 8; off <= 32; off <<= 1) {
        a0 += __shfl_xor(a0, off); a1 += __shfl_xor(a1, off);
        a2 += __shfl_xor(a2, off); a3 += __shfl_xor(a3, off);
        a4 += __shfl_xor(a4, off); a5 += __shfl_xor(a5, off);
        a6 += __shfl_xor(a6, off); a7 += __shfl_xor(a7, off);
    }
    if (sub == 0) {   // lanes 0..7 of each wave hold feats [8r, 8r+8)
        float4 bA = ((const float4*)b1)[2 * r];
        float4 bB = ((const float4*)b1)[2 * r + 1];
        float4 vA = make_float4(fmaxf(a0 + bA.x, 0.f), fmaxf(a1 + bA.y, 0.f),
                                fmaxf(a2 + bA.z, 0.f), fmaxf(a3 + bA.w, 0.f));
        float4 vB = make_float4(fmaxf(a4 + bB.x, 0.f), fmaxf(a5 + bB.y, 0.f),
                                fmaxf(a6 + bB.z, 0.f), fmaxf(a7 + bB.w, 0.f));
        *(float4*)&hs[w][8 * r]     = vA;
        *(float4*)&hs[w][8 * r + 4] = vB;
    }
    __syncthreads();

    // gemm2 tail: 64 threads compute 4 nodes x 16 classes
    if (threadIdx.x < 64) {
        const int l = threadIdx.x >> 4;
        const int c = threadIdx.x & 15;
        float a = 0.f;
#pragma unroll
        for (int k = 0; k < NHID; ++k) a += hs[l][k] * w2s[k * NCLASS + c];
        s2[(size_t)(blockIdx.x * 4 + l) * NCLASS + c] = f2bf(a);
    }
}

// ---------------------------------------------------------------------------
// out = log_softmax(gather(s2) + b2)
// 4 indep nodes/wave, 16 lanes/node, 8-edge unroll -> 32 loads in flight.
// ---------------------------------------------------------------------------
__global__ __launch_bounds__(256) void k_agg2lsm(const int* __restrict__ row_ptr,
                                                 const unsigned int* __restrict__ edge2,
                                                 const unsigned short* __restrict__ s2,
                                                 const float* __restrict__ b2,
                                                 float* __restrict__ out) {
    const int n = blockIdx.x * 16 + (threadIdx.x >> 4);
    const int c = threadIdx.x & 15;
    const int beg = row_ptr[n], end = row_ptr[n + 1];
    float acc = 0.f;
    int p = beg;
    for (; p + 8 <= end; p += 8) {
        unsigned int e0 = edge2[p],     e1 = edge2[p + 1];
        unsigned int e2 = edge2[p + 2], e3 = edge2[p + 3];
        unsigned int e4 = edge2[p + 4], e5 = edge2[p + 5];
        unsigned int e6 = edge2[p + 6], e7 = edge2[p + 7];
        acc += wdec(e0) * bf2f(s2[(size_t)(e0 & 0x1FFFF) * NCLASS + c]);
        acc += wdec(e1) * bf2f(s2[(size_t)(e1 & 0x1FFFF) * NCLASS + c]);
        acc += wdec(e2) * bf2f(s2[(size_t)(e2 & 0x1FFFF) * NCLASS + c]);
        acc += wdec(e3) * bf2f(s2[(size_t)(e3 & 0x1FFFF) * NCLASS + c]);
        acc += wdec(e4) * bf2f(s2[(size_t)(e4 & 0x1FFFF) * NCLASS + c]);
        acc += wdec(e5) * bf2f(s2[(size_t)(e5 & 0x1FFFF) * NCLASS + c]);
        acc += wdec(e6) * bf2f(s2[(size_t)(e6 & 0x1FFFF) * NCLASS + c]);
        acc += wdec(e7) * bf2f(s2[(size_t)(e7 & 0x1FFFF) * NCLASS + c]);
    }
    if (p < end) {   // masked epilogue, 1..7 edges
#pragma unroll
        for (int k = 0; k < 7; ++k) {
            int idx = p + k;
            unsigned int e = edge2[min(idx, end - 1)];
            float wv = (idx < end) ? wdec(e) : 0.f;
            acc += wv * bf2f(s2[(size_t)(e & 0x1FFFF) * NCLASS + c]);
        }
    }
    float v = acc + b2[c];
    float m = v;
#pragma unroll
    for (int off = 8; off >= 1; off >>= 1) m = fmaxf(m, __shfl_xor(m, off, 16));
    float s = __expf(v - m);
#pragma unroll
    for (int off = 8; off >= 1; off >>= 1) s += __shfl_xor(s, off, 16);
    out[(size_t)n * NCLASS + c] = v - m - __logf(s);
}

extern "C" void kernel_launch(void* const* d_in, const int* in_sizes, int n_in,
                              void* d_out, int out_size, void* d_ws, size_t ws_size,
                              hipStream_t stream) {
    const float* x   = (const float*)d_in[0];
    const int*   src = (const int*)d_in[1];
    const int*   dst = (const int*)d_in[2];
    const float* ew  = (const float*)d_in[3];
    const float* W1  = (const float*)d_in[4];
    const float* b1  = (const float*)d_in[5];
    const float* W2  = (const float*)d_in[6];
    const float* b2  = (const float*)d_in[7];
    float* out = (float*)d_out;

    // ws layout (~36 MB): s1 bf16[N*64] | s2 bf16[N*16] | edgeA int2[E] |
    // edgeB uint[E] | row_ptr[N+1] | bucket_cnt[196] | bucket_ptr[197] | fill[196]
    unsigned short* s1 = (unsigned short*)d_ws;
    unsigned short* s2 = s1 + (size_t)N_NODES * NHID;
    int2* edgeA        = (int2*)(s2 + (size_t)N_NODES * NCLASS);
    unsigned int* edgeB = (unsigned int*)(edgeA + N_EDGES);
    int*  row_ptr      = (int*)(edgeB + N_EDGES);
    int*  bucket_cnt   = row_ptr + (N_NODES + 1);
    int*  bucket_ptr   = bucket_cnt + NBUCK;
    int*  fill         = bucket_ptr + (NBUCK + 1);

    hipMemsetAsync(bucket_cnt, 0, sizeof(int) * NBUCK, stream);

    k_gemm1_hist<<<NB_GEMM1 + NB_SCAT, 256, 0, stream>>>(x, W1, s1, dst, bucket_cnt);
    k_bscan     <<<1, 256, 0, stream>>>(bucket_cnt, bucket_ptr, fill, row_ptr);
    k_bscatter  <<<NB_SCAT, 256, 0, stream>>>(dst, src, ew, fill, edgeA);
    k_bsort     <<<NBUCK, 256, 0, stream>>>(bucket_ptr, edgeA, edgeB, row_ptr);

    k_agg1g2 <<<N_NODES / 4, 256, 0, stream>>>(row_ptr, edgeB, s1, b1, W2, s2);
    k_agg2lsm<<<N_NODES / 16, 256, 0, stream>>>(row_ptr, edgeB, s2, b2, out);
}

// Round 10
// 260.344 us; speedup vs baseline: 2.5295x; 1.0291x over previous
//
#include <hip/hip_runtime.h>

#define N_NODES 100000
#define N_EDGES 1600000
#define NFEAT 128
#define NHID 64
#define NCLASS 16

#define BSHIFT 8                                   // 256 nodes per bucket
#define BUCK_NODES 256
#define NBUCK ((N_NODES + BUCK_NODES - 1) >> BSHIFT)   // 391
#define EDGE_TILE 2048
#define NB_SCAT ((N_EDGES + EDGE_TILE - 1) / EDGE_TILE) // 782
#define N_TILES (N_NODES / 64 + 1)                      // 1563 tiles of 64 nodes
#define NB_GEMM1 782                                    // grid-stride: 2 tiles/block

typedef __attribute__((ext_vector_type(8))) short short8;
typedef __attribute__((ext_vector_type(4))) float float4v;

__device__ __forceinline__ float bf2f(unsigned short u) {
    return __uint_as_float(((unsigned int)u) << 16);
}
__device__ __forceinline__ float bflo(unsigned int u) {
    return __uint_as_float(u << 16);
}
__device__ __forceinline__ float bfhi(unsigned int u) {
    return __uint_as_float(u & 0xFFFF0000u);
}
__device__ __forceinline__ unsigned short f2bf(float f) {
    unsigned int b = __float_as_uint(f);
    b += 0x7FFFu + ((b >> 16) & 1u);   // RNE
    return (unsigned short)(b >> 16);
}
// packed edge: src in bits [0,17), weight fixed-point 15b in [17,32)
__device__ __forceinline__ float wdec(unsigned int u) {
    return (float)(u >> 17) * (1.0f / 32767.0f);
}

// ---------------------------------------------------------------------------
// Fused: MFMA gemm1 (blocks 0..781, grid-stride over 64-node tiles)
//        + bucket histogram (blocks 782..1563)
// ---------------------------------------------------------------------------
__global__ __launch_bounds__(256) void k_gemm1_hist(const float* __restrict__ x,
                                                    const float* __restrict__ W1,
                                                    unsigned short* __restrict__ s1,
                                                    const int* __restrict__ dst,
                                                    int* __restrict__ bucket_cnt) {
    __shared__ unsigned short w1t[64][136];   // [n][k], padded for alignment
    __shared__ int hist[NBUCK];
    if (blockIdx.x >= NB_GEMM1) {
        // --- histogram part ---
        const int bid = blockIdx.x - NB_GEMM1;
        for (int i = threadIdx.x; i < NBUCK; i += 256) hist[i] = 0;
        __syncthreads();
        const int base = bid * EDGE_TILE;
        for (int i = threadIdx.x; i < EDGE_TILE; i += 256) {
            int e = base + i;
            if (e < N_EDGES) atomicAdd(&hist[dst[e] >> BSHIFT], 1);
        }
        __syncthreads();
        for (int i = threadIdx.x; i < NBUCK; i += 256)
            if (hist[i]) atomicAdd(&bucket_cnt[i], hist[i]);
        return;
    }
    // --- gemm1 part ---
    for (int i = threadIdx.x; i < NFEAT * NHID; i += 256) {
        int n = i & 63, k = i >> 6;
        w1t[n][k] = f2bf(W1[k * NHID + n]);
    }
    __syncthreads();

    const int lane = threadIdx.x & 63;
    const int wv   = threadIdx.x >> 6;
    const int m    = lane & 15;        // node-row / B-col within tile
    const int quad = lane >> 4;        // k-octet selector

    short8 bfrag[4][4];
#pragma unroll
    for (int kt = 0; kt < 4; ++kt)
#pragma unroll
        for (int nt = 0; nt < 4; ++nt)
            bfrag[kt][nt] = *(const short8*)&w1t[nt * 16 + m][kt * 32 + quad * 8];

    for (int tile = blockIdx.x; tile < N_TILES; tile += NB_GEMM1) {
        const int node0 = tile * 64 + wv * 16;
        if (node0 >= N_NODES) continue;
        const float4* xr = (const float4*)(x + (size_t)node0 * NFEAT);
        float4v acc[4] = {{0.f,0.f,0.f,0.f},{0.f,0.f,0.f,0.f},
                          {0.f,0.f,0.f,0.f},{0.f,0.f,0.f,0.f}};
#pragma unroll
        for (int kt = 0; kt < 4; ++kt) {
            float4 f0 = xr[m * 32 + kt * 8 + quad * 2];
            float4 f1 = xr[m * 32 + kt * 8 + quad * 2 + 1];
            short8 a;
            a[0] = (short)f2bf(f0.x); a[1] = (short)f2bf(f0.y);
            a[2] = (short)f2bf(f0.z); a[3] = (short)f2bf(f0.w);
            a[4] = (short)f2bf(f1.x); a[5] = (short)f2bf(f1.y);
            a[6] = (short)f2bf(f1.z); a[7] = (short)f2bf(f1.w);
#pragma unroll
            for (int nt = 0; nt < 4; ++nt)
                acc[nt] = __builtin_amdgcn_mfma_f32_16x16x32_bf16(
                    a, bfrag[kt][nt], acc[nt], 0, 0, 0);
        }
#pragma unroll
        for (int nt = 0; nt < 4; ++nt)
#pragma unroll
            for (int i = 0; i < 4; ++i)
                s1[(size_t)(node0 + quad * 4 + i) * NHID + nt * 16 + m] =
                    f2bf(acc[nt][i]);
    }
}

// ---------------------------------------------------------------------------
// Exclusive scan of 391 bucket counts (single block, 2 per thread)
// ---------------------------------------------------------------------------
__global__ __launch_bounds__(256) void k_bscan(const int* __restrict__ bucket_cnt,
                                               int* __restrict__ bucket_ptr,
                                               int* __restrict__ fill,
                                               int* __restrict__ row_ptr) {
    __shared__ int ts[256];
    const int i0 = threadIdx.x * 2, i1 = i0 + 1;
    int v0 = (i0 < NBUCK) ? bucket_cnt[i0] : 0;
    int v1 = (i1 < NBUCK) ? bucket_cnt[i1] : 0;
    ts[threadIdx.x] = v0 + v1;
    __syncthreads();
    for (int off = 1; off < 256; off <<= 1) {
        int t = (threadIdx.x >= off) ? ts[threadIdx.x - off] : 0;
        __syncthreads();
        ts[threadIdx.x] += t;
        __syncthreads();
    }
    int excl = threadIdx.x ? ts[threadIdx.x - 1] : 0;
    if (i0 < NBUCK) { bucket_ptr[i0] = excl;      fill[i0] = excl; }
    if (i1 < NBUCK) { bucket_ptr[i1] = excl + v0; fill[i1] = excl + v0; }
    if (threadIdx.x == 0) { bucket_ptr[NBUCK] = N_EDGES; row_ptr[N_NODES] = N_EDGES; }
}

// ---------------------------------------------------------------------------
// Bucket-scatter. 782 blocks x 2048 edges: ~3 blocks/CU, 8 serial iters.
// edgeA record: (src 17b | local_dst 8b, fp32 weight)
// ---------------------------------------------------------------------------
__global__ __launch_bounds__(256) void k_bscatter(const int* __restrict__ dst,
                                                  const int* __restrict__ src,
                                                  const float* __restrict__ ew,
                                                  int* __restrict__ fill,
                                                  int2* __restrict__ edgeA) {
    __shared__ int hist[NBUCK], bbase[NBUCK], bfill[NBUCK];
    for (int i = threadIdx.x; i < NBUCK; i += 256) { hist[i] = 0; bfill[i] = 0; }
    __syncthreads();
    const int base = blockIdx.x * EDGE_TILE;
    for (int i = threadIdx.x; i < EDGE_TILE; i += 256) {
        int e = base + i;
        if (e < N_EDGES) atomicAdd(&hist[dst[e] >> BSHIFT], 1);
    }
    __syncthreads();
    for (int i = threadIdx.x; i < NBUCK; i += 256)
        bbase[i] = hist[i] ? atomicAdd(&fill[i], hist[i]) : 0;
    __syncthreads();
    for (int i = threadIdx.x; i < EDGE_TILE; i += 256) {
        int e = base + i;
        if (e >= N_EDGES) break;
        int d = dst[e];
        int b = d >> BSHIFT;
        int r = atomicAdd(&bfill[b], 1);
        edgeA[bbase[b] + r] = make_int2(src[e] | ((d & (BUCK_NODES - 1)) << 17),
                                        __float_as_int(ew[e]));
    }
}

// ---------------------------------------------------------------------------
// In-bucket exact sort by dst. 391 blocks, ~4100 edges each, 16 serial iters.
// Emits row_ptr + packed 4 B records edgeB: src(17b) | w15(15b)
// ---------------------------------------------------------------------------
__global__ __launch_bounds__(256) void k_bsort(const int* __restrict__ bucket_ptr,
                                               const int2* __restrict__ edgeA,
                                               unsigned int* __restrict__ edgeB,
                                               int* __restrict__ row_ptr) {
    __shared__ int hist[BUCK_NODES], rstart[BUCK_NODES], lfill[BUCK_NODES];
    __shared__ int ts[256];
    const int b = blockIdx.x;
    const int beg = bucket_ptr[b], end = bucket_ptr[b + 1];
    hist[threadIdx.x] = 0; lfill[threadIdx.x] = 0;
    __syncthreads();
    for (int p = beg + threadIdx.x; p < end; p += 256)
        atomicAdd(&hist[edgeA[p].x >> 17], 1);
    __syncthreads();
    int a0 = hist[threadIdx.x];
    ts[threadIdx.x] = a0;
    __syncthreads();
    for (int off = 1; off < 256; off <<= 1) {
        int t = (threadIdx.x >= off) ? ts[threadIdx.x - off] : 0;
        __syncthreads();
        ts[threadIdx.x] += t;
        __syncthreads();
    }
    int excl = threadIdx.x ? ts[threadIdx.x - 1] : 0;
    rstart[threadIdx.x] = excl;
    __syncthreads();
    const int node0 = b << BSHIFT;
    {
        int n = node0 + threadIdx.x;
        if (n < N_NODES) row_ptr[n] = beg + excl;
    }
    for (int p = beg + threadIdx.x; p < end; p += 256) {
        int2 e = edgeA[p];
        int ld = e.x >> 17;
        int r = atomicAdd(&lfill[ld], 1);
        unsigned int w15 = (unsigned int)(__int_as_float(e.y) * 32767.0f + 0.5f);
        edgeB[beg + rstart[ld] + r] = (unsigned int)(e.x & 0x1FFFF) | (w15 << 17);
    }
}

// ---------------------------------------------------------------------------
// Fused: h = relu(gather(s1) + b1);  s2 = bf16(h @ W2)   (unchanged from R8)
// ---------------------------------------------------------------------------
__global__ __launch_bounds__(256) void k_agg1g2(const int* __restrict__ row_ptr,
                                                const unsigned int* __restrict__ edge2,
                                                const unsigned short* __restrict__ s1,
                                                const float* __restrict__ b1,
                                                const float* __restrict__ W2,
                                                unsigned short* __restrict__ s2) {
    __shared__ float hs[4][68];
    __shared__ float w2s[NHID * NCLASS];
    for (int i = threadIdx.x; i < NHID * NCLASS; i += 256) w2s[i] = W2[i];

    const uint4* __restrict__ s1u4 = (const uint4*)s1;   // row = 8 uint4 (64 bf16)
    const int w   = threadIdx.x >> 6;
    const int n   = blockIdx.x * 4 + w;
    const int sub = (threadIdx.x >> 3) & 7;
    const int r   = threadIdx.x & 7;

    const int beg = row_ptr[n], end = row_ptr[n + 1];
    float a0 = 0, a1 = 0, a2 = 0, a3 = 0, a4 = 0, a5 = 0, a6 = 0, a7 = 0;

    int p = beg;
    for (; p + 16 <= end; p += 16) {
        unsigned int e0 = edge2[p + sub];
        unsigned int e1 = edge2[p + sub + 8];
        uint4 u0 = s1u4[(size_t)(e0 & 0x1FFFF) * 8 + r];
        uint4 u1 = s1u4[(size_t)(e1 & 0x1FFFF) * 8 + r];
        float w0 = wdec(e0), w1 = wdec(e1);
        a0 += w0 * bflo(u0.x); a1 += w0 * bfhi(u0.x);
        a2 += w0 * bflo(u0.y); a3 += w0 * bfhi(u0.y);
        a4 += w0 * bflo(u0.z); a5 += w0 * bfhi(u0.z);
        a6 += w0 * bflo(u0.w); a7 += w0 * bfhi(u0.w);
        a0 += w1 * bflo(u1.x); a1 += w1 * bfhi(u1.x);
        a2 += w1 * bflo(u1.y); a3 += w1 * bfhi(u1.y);
        a4 += w1 * bflo(u1.z); a5 += w1 * bfhi(u1.z);
        a6 += w1 * bflo(u1.w); a7 += w1 * bfhi(u1.w);
    }
    if (p < end) {
        int i0 = p + sub, i1 = p + sub + 8;
        int j0 = min(i0, end - 1), j1 = min(i1, end - 1);
        unsigned int e0 = edge2[j0];
        unsigned int e1 = edge2[j1];
        uint4 u0 = s1u4[(size_t)(e0 & 0x1FFFF) * 8 + r];
        uint4 u1 = s1u4[(size_t)(e1 & 0x1FFFF) * 8 + r];
        float w0 = (i0 < end) ? wdec(e0) : 0.f;
        float w1 = (i1 < end) ? wdec(e1) : 0.f;
        a0 += w0 * bflo(u0.x); a1 += w0 * bfhi(u0.x);
        a2 += w0 * bflo(u0.y); a3 += w0 * bfhi(u0.y);
        a4 += w0 * bflo(u0.z); a5 += w0 * bfhi(u0.z);
        a6 += w0 * bflo(u0.w); a7 += w0 * bfhi(u0.w);
        a0 += w1 * bflo(u1.x); a1 += w1 * bfhi(u1.x);
        a2 += w1 * bflo(u1.y); a3 += w1 * bfhi(u1.y);
        a4 += w1 * bflo(u1.z); a5 += w1 * bfhi(u1.z);
        a6 += w1 * bflo(u1.w); a7 += w1 * bfhi(u1.w);
    }
#pragma unroll
    for (int off = 8; off <= 32; off <<= 1) {
        a0 += __shfl_xor(a0, off); a1 += __shfl_xor(a1, off);
        a2 += __shfl_xor(a2, off); a3 += __shfl_xor(a3, off);
        a4 += __shfl_xor(a4, off); a5 += __shfl_xor(a5, off);
        a6 += __shfl_xor(a6, off); a7 += __shfl_xor(a7, off);
    }
    if (sub == 0) {
        float4 bA = ((const float4*)b1)[2 * r];
        float4 bB = ((const float4*)b1)[2 * r + 1];
        float4 vA = make_float4(fmaxf(a0 + bA.x, 0.f), fmaxf(a1 + bA.y, 0.f),
                                fmaxf(a2 + bA.z, 0.f), fmaxf(a3 + bA.w, 0.f));
        float4 vB = make_float4(fmaxf(a4 + bB.x, 0.f), fmaxf(a5 + bB.y, 0.f),
                                fmaxf(a6 + bB.z, 0.f), fmaxf(a7 + bB.w, 0.f));
        *(float4*)&hs[w][8 * r]     = vA;
        *(float4*)&hs[w][8 * r + 4] = vB;
    }
    __syncthreads();

    if (threadIdx.x < 64) {
        const int l = threadIdx.x >> 4;
        const int c = threadIdx.x & 15;
        float a = 0.f;
#pragma unroll
        for (int k = 0; k < NHID; ++k) a += hs[l][k] * w2s[k * NCLASS + c];
        s2[(size_t)(blockIdx.x * 4 + l) * NCLASS + c] = f2bf(a);
    }
}

// ---------------------------------------------------------------------------
// out = log_softmax(gather(s2) + b2)
// 8 nodes/wave, 8 lanes/node (lane r = classes 2r,2r+1 as one uint).
// Gathers are 32 B-contiguous per row -> 256 B/instruction; 8 indep chains.
// ---------------------------------------------------------------------------
__global__ __launch_bounds__(256) void k_agg2lsm(const int* __restrict__ row_ptr,
                                                 const unsigned int* __restrict__ edge2,
                                                 const unsigned short* __restrict__ s2,
                                                 const float* __restrict__ b2,
                                                 float* __restrict__ out) {
    const unsigned int* __restrict__ s2u = (const unsigned int*)s2;  // row = 8 uints
    const int n = blockIdx.x * 32 + (threadIdx.x >> 3);
    const int r = threadIdx.x & 7;
    const int beg = row_ptr[n], end = row_ptr[n + 1];
    float a0 = 0.f, a1 = 0.f;
    int p = beg;
    for (; p + 8 <= end; p += 8) {
        unsigned int ee[8];
#pragma unroll
        for (int k = 0; k < 8; ++k) ee[k] = edge2[p + k];
#pragma unroll
        for (int k = 0; k < 8; ++k) {
            unsigned int u = s2u[(size_t)(ee[k] & 0x1FFFF) * 8 + r];
            float wv = wdec(ee[k]);
            a0 += wv * bflo(u);
            a1 += wv * bfhi(u);
        }
    }
    if (p < end) {   // masked epilogue, 1..7 edges
        unsigned int ee[8];
        float wv[8];
#pragma unroll
        for (int k = 0; k < 8; ++k) {
            int idx = p + k;
            ee[k] = edge2[min(idx, end - 1)];
            wv[k] = (idx < end) ? wdec(ee[k]) : 0.f;
        }
#pragma unroll
        for (int k = 0; k < 8; ++k) {
            unsigned int u = s2u[(size_t)(ee[k] & 0x1FFFF) * 8 + r];
            a0 += wv[k] * bflo(u);
            a1 += wv[k] * bfhi(u);
        }
    }
    float v0 = a0 + b2[2 * r];
    float v1 = a1 + b2[2 * r + 1];
    float m = fmaxf(v0, v1);
#pragma unroll
    for (int off = 4; off >= 1; off >>= 1) m = fmaxf(m, __shfl_xor(m, off, 8));
    float s = __expf(v0 - m) + __expf(v1 - m);
#pragma unroll
    for (int off = 4; off >= 1; off >>= 1) s += __shfl_xor(s, off, 8);
    float ls = __logf(s);
    float2 o = make_float2(v0 - m - ls, v1 - m - ls);
    *(float2*)(out + (size_t)n * NCLASS + 2 * r) = o;
}

extern "C" void kernel_launch(void* const* d_in, const int* in_sizes, int n_in,
                              void* d_out, int out_size, void* d_ws, size_t ws_size,
                              hipStream_t stream) {
    const float* x   = (const float*)d_in[0];
    const int*   src = (const int*)d_in[1];
    const int*   dst = (const int*)d_in[2];
    const float* ew  = (const float*)d_in[3];
    const float* W1  = (const float*)d_in[4];
    const float* b1  = (const float*)d_in[5];
    const float* W2  = (const float*)d_in[6];
    const float* b2  = (const float*)d_in[7];
    float* out = (float*)d_out;

    // ws layout (~36 MB): s1 bf16[N*64] | s2 bf16[N*16] | edgeA int2[E] |
    // edgeB uint[E] | row_ptr[N+1] | bucket_cnt[391] | bucket_ptr[392] | fill[391]
    unsigned short* s1 = (unsigned short*)d_ws;
    unsigned short* s2 = s1 + (size_t)N_NODES * NHID;
    int2* edgeA        = (int2*)(s2 + (size_t)N_NODES * NCLASS);
    unsigned int* edgeB = (unsigned int*)(edgeA + N_EDGES);
    int*  row_ptr      = (int*)(edgeB + N_EDGES);
    int*  bucket_cnt   = row_ptr + (N_NODES + 1);
    int*  bucket_ptr   = bucket_cnt + NBUCK;
    int*  fill         = bucket_ptr + (NBUCK + 1);

    hipMemsetAsync(bucket_cnt, 0, sizeof(int) * NBUCK, stream);

    k_gemm1_hist<<<NB_GEMM1 + NB_SCAT, 256, 0, stream>>>(x, W1, s1, dst, bucket_cnt);
    k_bscan     <<<1, 256, 0, stream>>>(bucket_cnt, bucket_ptr, fill, row_ptr);
    k_bscatter  <<<NB_SCAT, 256, 0, stream>>>(dst, src, ew, fill, edgeA);
    k_bsort     <<<NBUCK, 256, 0, stream>>>(bucket_ptr, edgeA, edgeB, row_ptr);

    k_agg1g2 <<<N_NODES / 4, 256, 0, stream>>>(row_ptr, edgeB, s1, b1, W2, s2);
    k_agg2lsm<<<N_NODES / 32, 256, 0, stream>>>(row_ptr, edgeB, s2, b2, out);
}